// Round 9
// baseline (529.191 us; speedup 1.0000x reference)
//
#include <hip/hip_runtime.h>
#include <hip/hip_bf16.h>
#include <math.h>

#define N_NODES 50000
#define N_EDGES 800000
#define NP 50048   // N rounded up to 64
#define RB16 (NP / 16)  // 3128 row-blocks of 16
#define NB 196     // CSR buckets: (N + 255) >> 8
#define XB_W 424   // xb row stride (shorts): cols 16..421 of x_all (405) + pad
#define XB_K 405

typedef __hip_bfloat16 bf16;
typedef __attribute__((ext_vector_type(8))) short short8;
typedef __attribute__((ext_vector_type(4))) float f32x4;

__device__ __forceinline__ float lrelu(float x) { return x > 0.f ? x : 0.2f * x; }

__device__ __forceinline__ short f2b(float v) {
    bf16 h = __float2bfloat16(v);
    return *reinterpret_cast<short*>(&h);
}
__device__ __forceinline__ float lo_bf(unsigned u) { return __uint_as_float(u << 16); }
__device__ __forceinline__ float hi_bf(unsigned u) { return __uint_as_float(u & 0xFFFF0000u); }
__device__ __forceinline__ float b2f_s(unsigned short s) {
    return __uint_as_float(((unsigned)s) << 16);
}
__device__ __forceinline__ unsigned pack_bf(float v0, float v1) {
    unsigned a = (unsigned)(unsigned short)f2b(v0);
    unsigned b = (unsigned)(unsigned short)f2b(v1);
    return a | (b << 16);
}
__device__ __forceinline__ float sigm(float x) { return 1.f / (1.f + expf(-x)); }

// Fragment-major ("FM") layout for MFMA operands:
//   element (row, col) of an (Mp x Kp) operand lives at
//   ((row>>4)*KI + (col>>5))*512 + ((col>>3)&3)*128 + (row&15)*8 + (col&7)
__device__ __forceinline__ size_t fm_idx(int row, int c, int KIo) {
    return ((size_t)(row >> 4) * KIo + (c >> 5)) * 512 +
           (size_t)((c >> 3) & 3) * 128 + (size_t)(row & 15) * 8 + (c & 7);
}

// ---------------------------------------------------------------------------
// Streaming f32 -> bf16 row-major conversion of x_all cols [16, 421).
// Fully lane-contiguous on both read and write; rows >= nrows zero-filled.
// ---------------------------------------------------------------------------
__global__ __launch_bounds__(256) void pack_xb_kernel(
    const float* __restrict__ x, short* __restrict__ xb, int nrows)
{
    long long t = (long long)blockIdx.x * 256 + threadIdx.x;
    if (t >= (long long)NP * 53) return;
    int r = (int)(t / 53), c8 = (int)(t % 53) * 8;
    short8 tmp;
    const float* p = x + (size_t)r * 441 + 16 + c8;
    if (r < nrows && c8 + 8 <= XB_K) {
        f32x4 a = *(const f32x4*)p;
        f32x4 b = *(const f32x4*)(p + 4);
#pragma unroll
        for (int j = 0; j < 4; j++) tmp[j] = f2b(a[j]);
#pragma unroll
        for (int j = 0; j < 4; j++) tmp[4 + j] = f2b(b[j]);
    } else if (r < nrows && c8 < XB_K) {
#pragma unroll
        for (int j = 0; j < 8; j++) tmp[j] = (c8 + j < XB_K) ? f2b(p[j]) : (short)0;
    } else {
#pragma unroll
        for (int j = 0; j < 8; j++) tmp[j] = 0;
    }
    *(short8*)(xb + (size_t)r * XB_W + c8) = tmp;
}

// ---------------------------------------------------------------------------
// Batched f32 -> bf16 fragment-major packer for weight tensors.
// ---------------------------------------------------------------------------
struct PackDesc {
    const float* src;
    short* dst;
    int lda, M, K, CT, KI;
};
struct PackArgs {
    PackDesc d[16];
    unsigned long long sz[16];
    int n;
};

__global__ __launch_bounds__(256) void pack_all_kernel(PackArgs pa,
                                                       unsigned long long total)
{
    for (unsigned long long i =
             (unsigned long long)blockIdx.x * blockDim.x + threadIdx.x;
         i < total; i += (unsigned long long)gridDim.x * blockDim.x) {
        unsigned long long off = i;
        int s = 0;
        while (s < pa.n - 1 && off >= pa.sz[s]) { off -= pa.sz[s]; s++; }
        PackDesc D = pa.d[s];
        int j = (int)(off & 7);
        int lane = (int)((off >> 3) & 63);
        unsigned rem = (unsigned)(off >> 9);
        int ct = rem % (unsigned)D.CT;
        int ki = rem / (unsigned)D.CT;
        int r = ct * 16 + (lane & 15);
        int k = ki * 32 + (lane >> 4) * 8 + j;
        float v = (r < D.M && k < D.K) ? D.src[(size_t)r * D.lda + k] : 0.f;
        D.dst[off] = f2b(v);
    }
}

// ---------------------------------------------------------------------------
// Direct-from-global MFMA GEMM (fragment-major operands).
// ---------------------------------------------------------------------------
template <int ACT, int ODT, int CT, int KI, int SCORES>
__global__ __launch_bounds__(256) void dgemm_kernel(
    const short* __restrict__ A,
    const short* __restrict__ W,
    const float* __restrict__ bias,
    void* __restrict__ Cv, int ldc, int nrows, int M,
    const float* __restrict__ a_src, const float* __restrict__ a_dst,
    float* __restrict__ ssrc, float* __restrict__ sdst)
{
    int tid = threadIdx.x;
    int row0 = blockIdx.x * 64;
    int wv = tid >> 6, lane = tid & 63;
    int lrow = lane & 15, quad = lane >> 4;

    const short* Ap = A + ((size_t)((row0 >> 4) + wv) * KI) * 512 + (size_t)lane * 8;
    const short* Wp = W + (size_t)lane * 8;

    short8 areg[KI];
#pragma unroll
    for (int ki = 0; ki < KI; ki++) areg[ki] = *(const short8*)(Ap + (size_t)ki * 512);

    f32x4 acc[CT];
#pragma unroll
    for (int ct = 0; ct < CT; ct++)
#pragma unroll
        for (int i = 0; i < 4; i++) acc[ct][i] = 0.f;

#pragma unroll
    for (int ki = 0; ki < KI; ki++) {
        short8 breg[CT];
#pragma unroll
        for (int ct = 0; ct < CT; ct++)
            breg[ct] = *(const short8*)(Wp + ((size_t)ki * CT + ct) * 512);
#pragma unroll
        for (int ct = 0; ct < CT; ct++)
            acc[ct] = __builtin_amdgcn_mfma_f32_16x16x32_bf16(areg[ki], breg[ct], acc[ct], 0, 0, 0);
    }

    float* Cf = (float*)Cv;
    bf16*  Cb = (bf16*)Cv;
#pragma unroll
    for (int ct = 0; ct < CT; ct++) {
        int gcol = ct * 16 + lrow;
        if (gcol >= M) continue;
        float bv = bias ? bias[gcol] : 0.f;
#pragma unroll
        for (int i = 0; i < 4; i++) {
            int grow = row0 + wv * 16 + quad * 4 + i;
            if (grow >= nrows) continue;
            float v = acc[ct][i] + bv;
            if (ACT == 1) v = fmaxf(v, 0.f);
            if (ACT == 2) v = sigm(v);
            if (ODT == 1) Cb[(size_t)grow * ldc + gcol] = __float2bfloat16(v);
            else          Cf[(size_t)grow * ldc + gcol] = v;
        }
    }

    if (SCORES) {
        float as_c[CT], ad_c[CT];
#pragma unroll
        for (int ct = 0; ct < CT; ct++) {
            int gcol = ct * 16 + lrow;
            as_c[ct] = (gcol < M) ? a_src[gcol] : 0.f;
            ad_c[ct] = (gcol < M) ? a_dst[gcol] : 0.f;
        }
#pragma unroll
        for (int i = 0; i < 4; i++) {
            float ps = 0.f, pd = 0.f;
#pragma unroll
            for (int ct = 0; ct < CT; ct++) {
                ps = fmaf(acc[ct][i], as_c[ct], ps);
                pd = fmaf(acc[ct][i], ad_c[ct], pd);
            }
#pragma unroll
            for (int off = 8; off > 0; off >>= 1) {
                ps += __shfl_down(ps, off);
                pd += __shfl_down(pd, off);
            }
            if (lrow == 0) {
                int grow = row0 + wv * 16 + quad * 4 + i;
                if (grow < nrows) { ssrc[grow] = ps; sdst[grow] = pd; }
            }
        }
    }
}

// ---------------------------------------------------------------------------
// Fused 2-layer MLP branch body: out = relu(W2@sig(W1@a+b1)+b2).
// ADT=0: scalar f32 loads (tiny K). ADT=3: direct vectorized f32x4 loads.
// ADT=4: row-major bf16 loads from xb (one short8 per ki, 16 lines/instr —
// optimal). Out-of-K elements masked after the (in-bounds) vector load.
// W1/W2 fragment-major; output fragment-major.
// ---------------------------------------------------------------------------
template <int ADT, int CT1, int CT2, int KI1>
__device__ __forceinline__ void brmlp_body(
    short* sH,  // [64][CT1*16+8]
    const void* __restrict__ Av, int lda, int aoff,
    const short* __restrict__ W1p, const float* __restrict__ B1,
    const short* __restrict__ W2p, const float* __restrict__ B2,
    short* __restrict__ out, int KIo, int coff, int nrows, int K1)
{
    constexpr int M1 = CT1 * 16;
    constexpr int LDH = M1 + 8;
    constexpr int KI2 = M1 / 32;

    int tid = threadIdx.x;
    int row0 = blockIdx.x * 64;
    int wv = tid >> 6, lane = tid & 63;
    int lrow = lane & 15, quad = lane >> 4;

    // ---- phase 1 ----
    {
        short8 areg[KI1];
        if (ADT == 4) {
            const short* Xb = (const short*)Av;
            int arow = row0 + wv * 16 + lrow;
            const short* rp = Xb + (size_t)arow * lda + aoff;
#pragma unroll
            for (int ki = 0; ki < KI1; ki++) {
                int kb = ki * 32 + quad * 8;
                if (kb + 8 <= K1) {
                    areg[ki] = *(const short8*)(rp + kb);
                } else if (kb < K1) {
                    short8 v = *(const short8*)(rp + kb);
#pragma unroll
                    for (int j = 0; j < 8; j++)
                        areg[ki][j] = (kb + j < K1) ? v[j] : (short)0;
                } else {
#pragma unroll
                    for (int j = 0; j < 8; j++) areg[ki][j] = 0;
                }
            }
        } else if (ADT == 3) {
            const float* Af = (const float*)Av;
            int arow = row0 + wv * 16 + lrow;
            bool rok = arow < nrows;
            const float* rp = Af + (size_t)arow * lda + aoff;
#pragma unroll
            for (int ki = 0; ki < KI1; ki++) {
                int kb = ki * 32 + quad * 8;
                if (rok && kb + 8 <= K1) {
                    f32x4 a = *(const f32x4*)(rp + kb);
                    f32x4 b = *(const f32x4*)(rp + kb + 4);
#pragma unroll
                    for (int j = 0; j < 4; j++) areg[ki][j] = f2b(a[j]);
#pragma unroll
                    for (int j = 0; j < 4; j++) areg[ki][4 + j] = f2b(b[j]);
                } else if (rok && kb < K1) {
#pragma unroll
                    for (int j = 0; j < 8; j++)
                        areg[ki][j] = (kb + j < K1) ? f2b(rp[kb + j]) : (short)0;
                } else {
#pragma unroll
                    for (int j = 0; j < 8; j++) areg[ki][j] = 0;
                }
            }
        } else {
            const float* Af = (const float*)Av;
            int arow = row0 + wv * 16 + lrow;
            bool rok = arow < nrows;
#pragma unroll
            for (int ki = 0; ki < KI1; ki++)
#pragma unroll
                for (int j = 0; j < 8; j++) {
                    int k = ki * 32 + quad * 8 + j;
                    areg[ki][j] = (rok && k < K1)
                                      ? f2b(Af[(size_t)arow * lda + aoff + k])
                                      : (short)0;
                }
        }

        f32x4 acc[CT1];
#pragma unroll
        for (int ct = 0; ct < CT1; ct++)
#pragma unroll
            for (int i = 0; i < 4; i++) acc[ct][i] = 0.f;

#pragma unroll
        for (int ki = 0; ki < KI1; ki++) {
            short8 breg[CT1];
#pragma unroll
            for (int ct = 0; ct < CT1; ct++)
                breg[ct] = *(const short8*)(W1p + ((size_t)ki * CT1 + ct) * 512 +
                                            (size_t)lane * 8);
#pragma unroll
            for (int ct = 0; ct < CT1; ct++)
                acc[ct] = __builtin_amdgcn_mfma_f32_16x16x32_bf16(areg[ki], breg[ct], acc[ct], 0, 0, 0);
        }
#pragma unroll
        for (int ct = 0; ct < CT1; ct++) {
            int col = ct * 16 + lrow;
            float bv = B1[col];
#pragma unroll
            for (int i = 0; i < 4; i++)
                sH[(wv * 16 + quad * 4 + i) * LDH + col] = f2b(sigm(acc[ct][i] + bv));
        }
    }

    // ---- phase 2 (K2 = M1); per-wave rows, no barrier needed ----
    {
        f32x4 acc[CT2];
#pragma unroll
        for (int ct = 0; ct < CT2; ct++)
#pragma unroll
            for (int i = 0; i < 4; i++) acc[ct][i] = 0.f;

#pragma unroll
        for (int ki = 0; ki < KI2; ki++) {
            short8 a = *(short8*)&sH[(wv * 16 + lrow) * LDH + ki * 32 + quad * 8];
            short8 breg[CT2];
#pragma unroll
            for (int ct = 0; ct < CT2; ct++)
                breg[ct] = *(const short8*)(W2p + ((size_t)ki * CT2 + ct) * 512 +
                                            (size_t)lane * 8);
#pragma unroll
            for (int ct = 0; ct < CT2; ct++)
                acc[ct] = __builtin_amdgcn_mfma_f32_16x16x32_bf16(a, breg[ct], acc[ct], 0, 0, 0);
        }
#pragma unroll
        for (int ct = 0; ct < CT2; ct++) {
            int gcol = ct * 16 + lrow;
            float bv = B2[gcol];
            int c = coff + gcol;
#pragma unroll
            for (int i = 0; i < 4; i++) {
                int grow = row0 + wv * 16 + quad * 4 + i;
                if (grow >= nrows) continue;
                float v = fmaxf(acc[ct][i] + bv, 0.f);
                out[fm_idx(grow, c, KIo)] = f2b(v);
            }
        }
    }
}

template <int ADT, int CT1, int CT2, int KI1>
__global__ __launch_bounds__(256) void brmlp_kernel(
    const void* __restrict__ Av, int lda, int aoff,
    const short* __restrict__ W1p, const float* __restrict__ B1,
    const short* __restrict__ W2p, const float* __restrict__ B2,
    short* __restrict__ out, int KIo, int coff, int nrows, int K1)
{
    __shared__ short sH[64 * (CT1 * 16 + 8)];
    brmlp_body<ADT, CT1, CT2, KI1>(sH, Av, lda, aoff, W1p, B1, W2p, B2,
                                   out, KIo, coff, nrows, K1);
}

// sep1+sep2 fused into one launch (blockIdx.y selects the branch).
__global__ __launch_bounds__(256) void brmlp_pair_kernel(
    const void* __restrict__ Av, int lda,
    const short* __restrict__ W1a, const float* __restrict__ B1a,
    const short* __restrict__ W2a, const float* __restrict__ B2a,
    const short* __restrict__ W1b, const float* __restrict__ B1b,
    const short* __restrict__ W2b, const float* __restrict__ B2b,
    short* __restrict__ out, int KIo, int nrows)
{
    __shared__ short sH[64 * 72];
    if (blockIdx.y == 0)
        brmlp_body<0, 4, 4, 1>(sH, Av, lda, 1, W1a, B1a, W2a, B2a,
                               out, KIo, 0, nrows, 2);
    else
        brmlp_body<0, 4, 4, 1>(sH, Av, lda, 3, W1b, B1b, W2b, B2b,
                               out, KIo, 64, nrows, 13);
}

// ---------------------------------------------------------------------------
// Fused head: concat(gat3_out, lstm_h) -> lin1(relu) -> lin2(relu) -> lin3.
// ---------------------------------------------------------------------------
__global__ __launch_bounds__(256) void head_kernel(
    const short* __restrict__ xgs, const float* __restrict__ x_all,
    const float* __restrict__ wih, const float* __restrict__ bih,
    const float* __restrict__ bhh,
    const short* __restrict__ w1p, const float* __restrict__ b1,
    const short* __restrict__ w2p, const float* __restrict__ b2,
    const short* __restrict__ w3p, const float* __restrict__ b3,
    float* __restrict__ dout, int n)
{
    __shared__ short sW[20][200];
    __shared__ float sT[64][20];
    __shared__ short sH[64][72];
    __shared__ short sH2[64][72];
    __shared__ short sH3[64][72];

    int tid = threadIdx.x;
    int row0 = blockIdx.x * 64;
    int wv = tid >> 6, lane = tid & 63;
    int lrow = lane & 15, quad = lane >> 4;

    short8 axg[2];
#pragma unroll
    for (int ki = 0; ki < 2; ki++)
        axg[ki] = *(const short8*)(xgs + (((size_t)((row0 >> 4) + wv) * 2 + ki) * 64 +
                                          lane) * 8);

    for (int i = tid; i < 20 * 192; i += 256) {
        int k = i / 192, j = i % 192;
        int gate = j >> 6, jj = j & 63;
        int srow = (gate == 0) ? jj : (gate == 1 ? 128 + jj : 192 + jj);
        sW[k][j] = f2b(wih[srow * 20 + k]);
    }
    for (int i = tid; i < 64 * 20; i += 256) {
        int r = i / 20, k = i % 20;
        int grow = row0 + r;
        sT[r][k] = (grow < n) ? x_all[(size_t)grow * 441 + 421 + k] : 0.f;
    }
    __syncthreads();

    for (int p = 0; p < 16; p++) {
        int idx = p * 256 + tid;
        int r = idx >> 6, j = idx & 63;
        float gi = 0.f, gg = 0.f, go = 0.f;
#pragma unroll
        for (int k = 0; k < 20; k++) {
            float t = sT[r][k];
            gi = fmaf(t, b2f_s((unsigned short)sW[k][j]), gi);
            gg = fmaf(t, b2f_s((unsigned short)sW[k][64 + j]), gg);
            go = fmaf(t, b2f_s((unsigned short)sW[k][128 + j]), go);
        }
        gi += bih[j] + bhh[j];
        gg += bih[128 + j] + bhh[128 + j];
        go += bih[192 + j] + bhh[192 + j];
        float c = sigm(gi) * tanhf(gg);
        float h = sigm(go) * tanhf(c);
        sH[r][j] = f2b(h);
    }
    __syncthreads();

    f32x4 acc[4];
#pragma unroll
    for (int ct = 0; ct < 4; ct++)
#pragma unroll
        for (int i = 0; i < 4; i++) acc[ct][i] = 0.f;
#pragma unroll
    for (int ki = 0; ki < 4; ki++) {
        short8 a = (ki < 2) ? axg[ki]
                            : *(short8*)&sH[wv * 16 + lrow][(ki - 2) * 32 + quad * 8];
        short8 breg[4];
#pragma unroll
        for (int ct = 0; ct < 4; ct++)
            breg[ct] = *(const short8*)(w1p + ((size_t)ki * 4 + ct) * 512 +
                                        (size_t)lane * 8);
#pragma unroll
        for (int ct = 0; ct < 4; ct++)
            acc[ct] = __builtin_amdgcn_mfma_f32_16x16x32_bf16(a, breg[ct], acc[ct], 0, 0, 0);
    }
#pragma unroll
    for (int ct = 0; ct < 4; ct++) {
        int col = ct * 16 + lrow;
        float bv = b1[col];
#pragma unroll
        for (int i = 0; i < 4; i++)
            sH2[wv * 16 + quad * 4 + i][col] = f2b(fmaxf(acc[ct][i] + bv, 0.f));
    }

#pragma unroll
    for (int ct = 0; ct < 4; ct++)
#pragma unroll
        for (int i = 0; i < 4; i++) acc[ct][i] = 0.f;
#pragma unroll
    for (int ki = 0; ki < 2; ki++) {
        short8 a = *(short8*)&sH2[wv * 16 + lrow][ki * 32 + quad * 8];
        short8 breg[4];
#pragma unroll
        for (int ct = 0; ct < 4; ct++)
            breg[ct] = *(const short8*)(w2p + ((size_t)ki * 4 + ct) * 512 +
                                        (size_t)lane * 8);
#pragma unroll
        for (int ct = 0; ct < 4; ct++)
            acc[ct] = __builtin_amdgcn_mfma_f32_16x16x32_bf16(a, breg[ct], acc[ct], 0, 0, 0);
    }
#pragma unroll
    for (int ct = 0; ct < 4; ct++) {
        int col = ct * 16 + lrow;
        float bv = b2[col];
#pragma unroll
        for (int i = 0; i < 4; i++)
            sH3[wv * 16 + quad * 4 + i][col] = f2b(fmaxf(acc[ct][i] + bv, 0.f));
    }

#pragma unroll
    for (int ct = 0; ct < 4; ct++)
#pragma unroll
        for (int i = 0; i < 4; i++) acc[ct][i] = 0.f;
#pragma unroll
    for (int ki = 0; ki < 2; ki++) {
        short8 a = *(short8*)&sH3[wv * 16 + lrow][ki * 32 + quad * 8];
        short8 breg[4];
#pragma unroll
        for (int ct = 0; ct < 4; ct++)
            breg[ct] = *(const short8*)(w3p + ((size_t)ki * 4 + ct) * 512 +
                                        (size_t)lane * 8);
#pragma unroll
        for (int ct = 0; ct < 4; ct++)
            acc[ct] = __builtin_amdgcn_mfma_f32_16x16x32_bf16(a, breg[ct], acc[ct], 0, 0, 0);
    }
#pragma unroll
    for (int ct = 0; ct < 4; ct++) {
        int gcol = ct * 16 + lrow;
        if (gcol >= 56) continue;
        float bv = b3[gcol];
#pragma unroll
        for (int i = 0; i < 4; i++) {
            int grow = row0 + wv * 16 + quad * 4 + i;
            if (grow >= n) continue;
            dout[(size_t)grow * 56 + gcol] = acc[ct][i] + bv;
        }
    }
}

// ---------------------------------------------------------------------------
// Fused GAT aggregation, 8-deep gather unroll. Output fragment-major.
// ---------------------------------------------------------------------------
template <int FPL, int KIo>
__global__ __launch_bounds__(256) void gat_fused_kernel(
    const bf16* __restrict__ hw, const int* __restrict__ rowptr,
    const int* __restrict__ colidx, const float* __restrict__ ss,
    const float* __restrict__ sd, const float* __restrict__ bias,
    short* __restrict__ out, int n, int F)
{
    int wv = threadIdx.x >> 6, lane = threadIdx.x & 63;
    int node = blockIdx.x * 4 + wv;
    if (node >= n) return;
    const unsigned short* hwu = (const unsigned short*)hw;
    float sdn = sd[node];
    float wself = expf(lrelu(ss[node] + sdn));
    float a0, a1 = 0.f;
    if (FPL == 2) {
        unsigned u = *(const unsigned*)(hwu + (size_t)node * F + 2 * lane);
        a0 = wself * lo_bf(u);
        a1 = wself * hi_bf(u);
    } else {
        a0 = wself * b2f_s(hwu[(size_t)node * F + lane]);
    }
    int e0 = rowptr[node];
    int deg = rowptr[node + 1] - e0;
    float den_l = 0.f;
    for (int c0 = 0; c0 < deg; c0 += 64) {
        int mye = c0 + lane;
        int s = 0;
        float w = 0.f;
        if (mye < deg) {
            s = colidx[e0 + mye];
            w = expf(lrelu(ss[s] + sdn));
        }
        den_l += w;
        int cnt = min(64, deg - c0);
        int j = 0;
        for (; j + 7 < cnt; j += 8) {
            int sx[8];
            float wx[8];
#pragma unroll
            for (int q = 0; q < 8; q++) {
                sx[q] = __shfl(s, j + q);
                wx[q] = __shfl(w, j + q);
            }
            if (FPL == 2) {
                unsigned ux[8];
#pragma unroll
                for (int q = 0; q < 8; q++)
                    ux[q] = *(const unsigned*)(hwu + (size_t)sx[q] * F + 2 * lane);
#pragma unroll
                for (int q = 0; q < 8; q++) {
                    a0 = fmaf(wx[q], lo_bf(ux[q]), a0);
                    a1 = fmaf(wx[q], hi_bf(ux[q]), a1);
                }
            } else {
                float hx[8];
#pragma unroll
                for (int q = 0; q < 8; q++)
                    hx[q] = b2f_s(hwu[(size_t)sx[q] * F + lane]);
#pragma unroll
                for (int q = 0; q < 8; q++) a0 = fmaf(wx[q], hx[q], a0);
            }
        }
        for (; j + 3 < cnt; j += 4) {
            int s0 = __shfl(s, j), s1 = __shfl(s, j + 1);
            int s2 = __shfl(s, j + 2), s3 = __shfl(s, j + 3);
            float w0 = __shfl(w, j), w1v = __shfl(w, j + 1);
            float w2v = __shfl(w, j + 2), w3v = __shfl(w, j + 3);
            if (FPL == 2) {
                unsigned u0 = *(const unsigned*)(hwu + (size_t)s0 * F + 2 * lane);
                unsigned u1 = *(const unsigned*)(hwu + (size_t)s1 * F + 2 * lane);
                unsigned u2 = *(const unsigned*)(hwu + (size_t)s2 * F + 2 * lane);
                unsigned u3 = *(const unsigned*)(hwu + (size_t)s3 * F + 2 * lane);
                a0 = fmaf(w0, lo_bf(u0), a0);  a1 = fmaf(w0, hi_bf(u0), a1);
                a0 = fmaf(w1v, lo_bf(u1), a0); a1 = fmaf(w1v, hi_bf(u1), a1);
                a0 = fmaf(w2v, lo_bf(u2), a0); a1 = fmaf(w2v, hi_bf(u2), a1);
                a0 = fmaf(w3v, lo_bf(u3), a0); a1 = fmaf(w3v, hi_bf(u3), a1);
            } else {
                float h0 = b2f_s(hwu[(size_t)s0 * F + lane]);
                float h1 = b2f_s(hwu[(size_t)s1 * F + lane]);
                float h2 = b2f_s(hwu[(size_t)s2 * F + lane]);
                float h3 = b2f_s(hwu[(size_t)s3 * F + lane]);
                a0 = fmaf(w0, h0, a0);
                a0 = fmaf(w1v, h1, a0);
                a0 = fmaf(w2v, h2, a0);
                a0 = fmaf(w3v, h3, a0);
            }
        }
        for (; j < cnt; j++) {
            int s0 = __shfl(s, j);
            float w0 = __shfl(w, j);
            if (FPL == 2) {
                unsigned u0 = *(const unsigned*)(hwu + (size_t)s0 * F + 2 * lane);
                a0 = fmaf(w0, lo_bf(u0), a0);
                a1 = fmaf(w0, hi_bf(u0), a1);
            } else {
                a0 = fmaf(w0, b2f_s(hwu[(size_t)s0 * F + lane]), a0);
            }
        }
    }
#pragma unroll
    for (int off = 32; off > 0; off >>= 1) den_l += __shfl_xor(den_l, off);
    float inv = 1.f / (den_l + wself);
    int rb = node >> 4, nr = node & 15;
    if (FPL == 2) {
        float v0 = fmaxf(a0 * inv + bias[2 * lane], 0.f);
        float v1 = fmaxf(a1 * inv + bias[2 * lane + 1], 0.f);
        size_t uidx = ((size_t)rb * KIo + (lane >> 4)) * 256 +
                      (size_t)((lane >> 2) & 3) * 64 + nr * 4 + (lane & 3);
        ((unsigned*)out)[uidx] = pack_bf(v0, v1);
    } else {
        float v0 = fmaxf(a0 * inv + bias[lane], 0.f);
        size_t sidx = ((size_t)rb * KIo + (lane >> 5)) * 512 +
                      (size_t)((lane >> 3) & 3) * 128 + nr * 8 + (lane & 7);
        out[sidx] = f2b(v0);
    }
}

// ---------------------------------------------------------------------------
// Bucketed CSR build (write-amp-free):
//   bhist -> bscan -> bpart (bucket-partitioned pairs) -> bcsr (one block
//   per bucket: LDS per-node count + scan + scatter within a private window).
// ---------------------------------------------------------------------------
__global__ __launch_bounds__(256) void bhist_kernel(const int* __restrict__ dst,
                                                    int* __restrict__ bcnt, int e)
{
    __shared__ int l[NB];
    for (int i = threadIdx.x; i < NB; i += 256) l[i] = 0;
    __syncthreads();
    for (int i = blockIdx.x * blockDim.x + threadIdx.x; i < e;
         i += gridDim.x * blockDim.x)
        atomicAdd(&l[dst[i] >> 8], 1);
    __syncthreads();
    for (int i = threadIdx.x; i < NB; i += 256)
        if (l[i]) atomicAdd(&bcnt[i], l[i]);
}

__global__ __launch_bounds__(256) void bscan_kernel(
    const int* __restrict__ bcnt, int* __restrict__ boff,
    int* __restrict__ bcur, int* __restrict__ rowptr, int n, int e)
{
    __shared__ int tmp[256];
    int tid = threadIdx.x;
    int v = (tid < NB) ? bcnt[tid] : 0;
    tmp[tid] = v;
    __syncthreads();
    for (int off = 1; off < 256; off <<= 1) {
        int t = (tid >= off) ? tmp[tid - off] : 0;
        __syncthreads();
        tmp[tid] += t;
        __syncthreads();
    }
    int excl = tmp[tid] - v;
    if (tid < NB) { boff[tid] = excl; bcur[tid] = excl; }
    if (tid == 0) { boff[NB] = e; rowptr[n] = e; }
}

__global__ __launch_bounds__(256) void bpart_kernel(
    const int* __restrict__ src, const int* __restrict__ dst,
    int* __restrict__ bcur, int2* __restrict__ pairs, int e)
{
    __shared__ int lcnt[NB];
    __shared__ int lbase[NB];
    const int TILE = 2048;
    for (long long t0 = (long long)blockIdx.x * TILE; t0 < e;
         t0 += (long long)gridDim.x * TILE) {
        for (int i = threadIdx.x; i < NB; i += 256) lcnt[i] = 0;
        __syncthreads();
        int rank[8], bb[8], sv[8], dv[8];
#pragma unroll
        for (int k = 0; k < 8; k++) {
            int i = (int)t0 + k * 256 + threadIdx.x;
            bb[k] = -1;
            if (i < e) {
                int d = dst[i];
                sv[k] = src[i];
                dv[k] = d;
                bb[k] = d >> 8;
                rank[k] = atomicAdd(&lcnt[bb[k]], 1);
            }
        }
        __syncthreads();
        for (int i = threadIdx.x; i < NB; i += 256)
            lbase[i] = lcnt[i] ? atomicAdd(&bcur[i], lcnt[i]) : 0;
        __syncthreads();
#pragma unroll
        for (int k = 0; k < 8; k++)
            if (bb[k] >= 0)
                pairs[(size_t)lbase[bb[k]] + rank[k]] = make_int2(sv[k], dv[k]);
        __syncthreads();
    }
}

__global__ __launch_bounds__(256) void bcsr_kernel(
    const int2* __restrict__ pairs, const int* __restrict__ boff,
    int* __restrict__ rowptr, int* __restrict__ colidx, int n)
{
    __shared__ int ncnt[256];
    __shared__ int tmp[256];
    int tid = threadIdx.x, b = blockIdx.x;
    int base = boff[b], end = boff[b + 1];
    ncnt[tid] = 0;
    __syncthreads();
    for (int i = base + tid; i < end; i += 256)
        atomicAdd(&ncnt[pairs[i].y & 255], 1);
    __syncthreads();
    int v = ncnt[tid];
    tmp[tid] = v;
    __syncthreads();
    for (int off = 1; off < 256; off <<= 1) {
        int t = (tid >= off) ? tmp[tid - off] : 0;
        __syncthreads();
        tmp[tid] += t;
        __syncthreads();
    }
    int excl = base + tmp[tid] - v;
    int node = (b << 8) + tid;
    if (node < n) rowptr[node] = excl;
    __syncthreads();
    ncnt[tid] = excl;
    __syncthreads();
    for (int i = base + tid; i < end; i += 256) {
        int2 p = pairs[i];
        int pos = atomicAdd(&ncnt[p.y & 255], 1);
        colidx[pos] = p.x;
    }
}

// ---------------------------------------------------------------------------
// Legacy CSR build (fallback if workspace too small for the pairs buffer).
// ---------------------------------------------------------------------------
__global__ void count_kernel(const int* __restrict__ dst, int* __restrict__ cnt,
                             int e)
{
    for (int i = blockIdx.x * blockDim.x + threadIdx.x; i < e;
         i += gridDim.x * blockDim.x)
        atomicAdd(cnt + dst[i], 1);
}

#define SCAN_BLOCKS 256

__global__ __launch_bounds__(256) void scan_local_kernel(
    const int* __restrict__ cnt, int* __restrict__ rowptr,
    int* __restrict__ bsum, int n, int chunk)
{
    __shared__ int tmp[256];
    int b = blockIdx.x, tid = threadIdx.x;
    int i = b * chunk + tid;
    int v = (tid < chunk && i < n) ? cnt[i] : 0;
    tmp[tid] = v;
    __syncthreads();
    for (int off = 1; off < 256; off <<= 1) {
        int t = (tid >= off) ? tmp[tid - off] : 0;
        __syncthreads();
        tmp[tid] += t;
        __syncthreads();
    }
    if (tid < chunk && i < n) rowptr[i] = tmp[tid] - v;
    if (tid == 255) bsum[b] = tmp[255];
}

__global__ __launch_bounds__(256) void scan_bsums_kernel(
    int* __restrict__ bsum, int* __restrict__ rowptr, int n)
{
    __shared__ int tmp[256];
    int tid = threadIdx.x;
    int v = bsum[tid];
    tmp[tid] = v;
    __syncthreads();
    for (int off = 1; off < 256; off <<= 1) {
        int t = (tid >= off) ? tmp[tid - off] : 0;
        __syncthreads();
        tmp[tid] += t;
        __syncthreads();
    }
    bsum[tid] = tmp[tid] - v;
    if (tid == 255) rowptr[n] = tmp[255];
}

__global__ __launch_bounds__(256) void scan_add_kernel(
    int* __restrict__ rowptr, int* __restrict__ nextp,
    const int* __restrict__ bsum, int n, int chunk)
{
    int b = blockIdx.x, tid = threadIdx.x;
    int i = b * chunk + tid;
    if (tid < chunk && i < n) {
        int v = rowptr[i] + bsum[b];
        rowptr[i] = v;
        nextp[i] = v;
    }
}

__global__ void fill_kernel(const int* __restrict__ src,
                            const int* __restrict__ dst,
                            int* __restrict__ nextp, int* __restrict__ colidx,
                            int e)
{
    for (int i = blockIdx.x * blockDim.x + threadIdx.x; i < e;
         i += gridDim.x * blockDim.x) {
        int pos = atomicAdd(nextp + dst[i], 1);
        colidx[pos] = src[i];
    }
}

// ---------------------------------------------------------------------------
extern "C" void kernel_launch(void* const* d_in, const int* in_sizes, int n_in,
                              void* d_out, int out_size, void* d_ws,
                              size_t ws_size, hipStream_t stream)
{
    const int N = N_NODES;
    const int E = N_EDGES;

    const float* x_all = (const float*)d_in[0];
    const int* edges = (const int*)d_in[1];
    const int* e_src = edges;
    const int* e_dst = edges + E;

    const float* sep1_w = (const float*)d_in[2];  const float* sep1_b = (const float*)d_in[3];
    const float* sep2_w = (const float*)d_in[4];  const float* sep2_b = (const float*)d_in[5];
    const float* sep3_w = (const float*)d_in[6];  const float* sep3_b = (const float*)d_in[7];
    const float* sep4_w = (const float*)d_in[8];  const float* sep4_b = (const float*)d_in[9];
    const float* sep5_w = (const float*)d_in[10]; const float* sep5_b = (const float*)d_in[11];
    const float* sep6_w = (const float*)d_in[12]; const float* sep6_b = (const float*)d_in[13];
    const float* sep7_w = (const float*)d_in[14]; const float* sep7_b = (const float*)d_in[15];
    const float* sep8_w = (const float*)d_in[16]; const float* sep8_b = (const float*)d_in[17];
    const float* conv1_w = (const float*)d_in[18];
    const float* conv1_as = (const float*)d_in[19];
    const float* conv1_ad = (const float*)d_in[20];
    const float* conv1_b = (const float*)d_in[21];
    const float* conv2_w = (const float*)d_in[22];
    const float* conv2_as = (const float*)d_in[23];
    const float* conv2_ad = (const float*)d_in[24];
    const float* conv2_b = (const float*)d_in[25];
    const float* conv3_w = (const float*)d_in[26];
    const float* conv3_as = (const float*)d_in[27];
    const float* conv3_ad = (const float*)d_in[28];
    const float* conv3_b = (const float*)d_in[29];
    const float* lstm_wih = (const float*)d_in[30];
    const float* lstm_bih = (const float*)d_in[32];
    const float* lstm_bhh = (const float*)d_in[33];
    const float* lin1_w = (const float*)d_in[34]; const float* lin1_b = (const float*)d_in[35];
    const float* lin2_w = (const float*)d_in[36]; const float* lin2_b = (const float*)d_in[37];
    const float* lin3_w = (const float*)d_in[38]; const float* lin3_b = (const float*)d_in[39];

    char* ws = (char*)d_ws;
    size_t off = 0;
    auto alloc = [&](size_t bytes) {
        void* p = ws + off;
        off += (bytes + 255) & ~(size_t)255;
        return p;
    };
    short* x0 = (short*)alloc((size_t)NP * 384 * 2);  // FM concat / C ping / xg
    short* Bb = (short*)alloc((size_t)NP * 128 * 2);  // hw buffer (row-major)
    float* ssrc = (float*)alloc((size_t)N * 4);
    float* sdst = (float*)alloc((size_t)N * 4);
    int* rowptr = (int*)alloc((size_t)(N + 1) * 4);
    int* nextp  = (int*)alloc((size_t)N * 4);
    int* cnt    = (int*)alloc((size_t)N * 4);
    int* bsum   = (int*)alloc((size_t)SCAN_BLOCKS * 4);
    int* colidx = (int*)alloc((size_t)E * 4);
    int* bcnt   = (int*)alloc((size_t)NB * 4);
    int* boff   = (int*)alloc((size_t)(NB + 1) * 4);
    int* bcur   = (int*)alloc((size_t)NB * 4);

    short* conv1p = (short*)alloc((size_t)128 * 384 * 2);
    short* conv2p = (short*)alloc((size_t)128 * 128 * 2);
    short* conv3p = (short*)alloc((size_t)64 * 128 * 2);
    short* sep1p  = (short*)alloc((size_t)64 * 32 * 2);
    short* sep2p  = (short*)alloc((size_t)64 * 32 * 2);
    short* sep3p  = (short*)alloc((size_t)128 * 64 * 2);
    short* sep4p  = (short*)alloc((size_t)128 * 384 * 2);
    short* sep5p  = (short*)alloc((size_t)64 * 64 * 2);
    short* sep6p  = (short*)alloc((size_t)64 * 64 * 2);
    short* sep7p  = (short*)alloc((size_t)128 * 128 * 2);
    short* sep8p  = (short*)alloc((size_t)128 * 128 * 2);
    short* lin1p  = (short*)alloc((size_t)64 * 128 * 2);
    short* lin2p  = (short*)alloc((size_t)64 * 64 * 2);
    short* lin3p  = (short*)alloc((size_t)64 * 64 * 2);

    size_t need_pairs = off + (size_t)E * 8 + 1024;
    bool binfill = ws_size >= need_pairs;
    int2* pairs = binfill ? (int2*)alloc((size_t)E * 8) : nullptr;

    size_t need_xb = off + (size_t)NP * XB_W * 2 + 1024;
    bool packxb = ws_size >= need_xb;
    short* xb = packxb ? (short*)alloc((size_t)NP * XB_W * 2) : nullptr;

    short* C  = x0;   // GAT ping buffer (N,128) FM KIo=4
    short* xg = x0;   // GAT3 out (N,64) FM KIo=2

    dim3 blk(256);
    int gx = NP / 64;  // 782
    int nb4 = (N + 3) / 4;

    // --- CSR build ---
    if (binfill) {
        hipMemsetAsync(bcnt, 0, (size_t)NB * 4, stream);
        bhist_kernel<<<1024, 256, 0, stream>>>(e_dst, bcnt, E);
        bscan_kernel<<<1, 256, 0, stream>>>(bcnt, boff, bcur, rowptr, N, E);
        bpart_kernel<<<(E + 2047) / 2048, 256, 0, stream>>>(e_src, e_dst, bcur,
                                                            pairs, E);
        bcsr_kernel<<<NB, 256, 0, stream>>>(pairs, boff, rowptr, colidx, N);
    } else {
        int chunk = (N + SCAN_BLOCKS - 1) / SCAN_BLOCKS;
        hipMemsetAsync(cnt, 0, (size_t)N * 4, stream);
        count_kernel<<<1024, 256, 0, stream>>>(e_dst, cnt, E);
        scan_local_kernel<<<SCAN_BLOCKS, 256, 0, stream>>>(cnt, rowptr, bsum, N, chunk);
        scan_bsums_kernel<<<1, 256, 0, stream>>>(bsum, rowptr, N);
        scan_add_kernel<<<SCAN_BLOCKS, 256, 0, stream>>>(rowptr, nextp, bsum, N, chunk);
        fill_kernel<<<1024, 256, 0, stream>>>(e_src, e_dst, nextp, colidx, E);
    }

    // --- streaming bf16 conversion of x_all cols [16,421) ---
    if (packxb) {
        long long tot = (long long)NP * 53;
        pack_xb_kernel<<<(int)((tot + 255) / 256), blk, 0, stream>>>(x_all, xb, N);
    }

    // --- pack weights (fragment-major) ---
    {
        PackArgs pa{};
        unsigned long long total = 0;
        int np = 0;
        auto addp = [&](const float* src, short* dst, int lda, int M, int K,
                        int CT, int KI) {
            pa.d[np].src = src; pa.d[np].dst = dst; pa.d[np].lda = lda;
            pa.d[np].M = M; pa.d[np].K = K; pa.d[np].CT = CT; pa.d[np].KI = KI;
            pa.sz[np] = (unsigned long long)CT * KI * 512;
            total += pa.sz[np];
            np++;
        };
        addp(conv1_w, conv1p, 384, 128, 384, 8, 12);
        addp(sep4_w, sep4p, 365, 128, 365, 8, 12);
        addp(conv2_w, conv2p, 128, 128, 128, 8, 4);
        addp(sep7_w, sep7p, 128, 128, 128, 8, 4);
        addp(sep8_w, sep8p, 128, 128, 128, 8, 4);
        addp(conv3_w, conv3p, 128, 64, 128, 4, 4);
        addp(lin1_w, lin1p, 128, 64, 128, 4, 4);
        addp(sep3_w, sep3p, 40, 128, 40, 8, 2);
        addp(sep5_w, sep5p, 64, 64, 64, 4, 2);
        addp(sep6_w, sep6p, 64, 64, 64, 4, 2);
        addp(lin2_w, lin2p, 64, 64, 64, 4, 2);
        addp(lin3_w, lin3p, 64, 56, 64, 4, 2);
        addp(sep1_w, sep1p, 2, 64, 2, 4, 1);
        addp(sep2_w, sep2p, 13, 64, 13, 4, 1);
        pa.n = np;
        pack_all_kernel<<<512, 256, 0, stream>>>(pa, total);
    }

    // --- four fused MLP branches -> x0 (N,384) bf16, fragment-major ---
    brmlp_pair_kernel<<<dim3(gx, 2), blk, 0, stream>>>(
        x_all, 441, sep1p, sep1_b, sep5p, sep5_b,
        sep2p, sep2_b, sep6p, sep6_b, x0, 12, N);
    if (packxb) {
        brmlp_kernel<4, 8, 8, 2><<<gx, blk, 0, stream>>>(
            xb, XB_W, 0, sep3p, sep3_b, sep7p, sep7_b, x0, 12, 128, N, 40);
        brmlp_kernel<4, 8, 8, 12><<<gx, blk, 0, stream>>>(
            xb, XB_W, 40, sep4p, sep4_b, sep8p, sep8_b, x0, 12, 256, N, 365);
    } else {
        brmlp_kernel<3, 8, 8, 2><<<gx, blk, 0, stream>>>(
            x_all, 441, 16, sep3p, sep3_b, sep7p, sep7_b, x0, 12, 128, N, 40);
        brmlp_kernel<3, 8, 8, 12><<<gx, blk, 0, stream>>>(
            x_all, 441, 56, sep4p, sep4_b, sep8p, sep8_b, x0, 12, 256, N, 365);
    }

    // --- GAT layers (scores fused into GEMM epilogue; FM operand loads) ---
    dgemm_kernel<0, 1, 8, 12, 1><<<gx, blk, 0, stream>>>(
        x0, conv1p, nullptr, Bb, 128, N, 128,
        conv1_as, conv1_ad, ssrc, sdst);
    gat_fused_kernel<2, 4><<<nb4, 256, 0, stream>>>(
        (const bf16*)Bb, rowptr, colidx, ssrc, sdst, conv1_b, C, N, 128);

    dgemm_kernel<0, 1, 8, 4, 1><<<gx, blk, 0, stream>>>(
        C, conv2p, nullptr, Bb, 128, N, 128,
        conv2_as, conv2_ad, ssrc, sdst);
    gat_fused_kernel<2, 4><<<nb4, 256, 0, stream>>>(
        (const bf16*)Bb, rowptr, colidx, ssrc, sdst, conv2_b, C, N, 128);

    dgemm_kernel<0, 1, 4, 4, 1><<<gx, blk, 0, stream>>>(
        C, conv3p, nullptr, Bb, 64, N, 64,
        conv3_as, conv3_ad, ssrc, sdst);
    gat_fused_kernel<1, 2><<<nb4, 256, 0, stream>>>(
        (const bf16*)Bb, rowptr, colidx, ssrc, sdst, conv3_b, xg, N, 64);

    // --- fused head: lstm + lin1 + lin2 + lin3 ---
    head_kernel<<<gx, blk, 0, stream>>>(
        xg, x_all, lstm_wih, lstm_bih, lstm_bhh,
        lin1p, lin1_b, lin2p, lin2_b, lin3p, lin3_b,
        (float*)d_out, N);
}

// Round 10
// 510.067 us; speedup vs baseline: 1.0375x; 1.0375x over previous
//
#include <hip/hip_runtime.h>
#include <hip/hip_bf16.h>
#include <math.h>

#define N_NODES 50000
#define N_EDGES 800000
#define NP 50048   // N rounded up to 64
#define RB16 (NP / 16)  // 3128 row-blocks of 16
#define NB 196     // CSR buckets: (N + 255) >> 8

typedef __hip_bfloat16 bf16;
typedef __attribute__((ext_vector_type(8))) short short8;
typedef __attribute__((ext_vector_type(4))) float f32x4;

__device__ __forceinline__ float lrelu(float x) { return x > 0.f ? x : 0.2f * x; }

__device__ __forceinline__ short f2b(float v) {
    bf16 h = __float2bfloat16(v);
    return *reinterpret_cast<short*>(&h);
}
__device__ __forceinline__ float lo_bf(unsigned u) { return __uint_as_float(u << 16); }
__device__ __forceinline__ float hi_bf(unsigned u) { return __uint_as_float(u & 0xFFFF0000u); }
__device__ __forceinline__ float b2f_s(unsigned short s) {
    return __uint_as_float(((unsigned)s) << 16);
}
__device__ __forceinline__ unsigned pack_bf(float v0, float v1) {
    unsigned a = (unsigned)(unsigned short)f2b(v0);
    unsigned b = (unsigned)(unsigned short)f2b(v1);
    return a | (b << 16);
}
__device__ __forceinline__ float sigm(float x) { return 1.f / (1.f + expf(-x)); }

// Fragment-major ("FM") layout for MFMA operands:
//   element (row, col) of an (Mp x Kp) operand lives at
//   ((row>>4)*KI + (col>>5))*512 + ((col>>3)&3)*128 + (row&15)*8 + (col&7)
__device__ __forceinline__ size_t fm_idx(int row, int c, int KIo) {
    return ((size_t)(row >> 4) * KIo + (c >> 5)) * 512 +
           (size_t)((c >> 3) & 3) * 128 + (size_t)(row & 15) * 8 + (c & 7);
}

// ---------------------------------------------------------------------------
// LDS-tiled transposing packer: x_all cols [16,421) -> FM xs4 (sep4 slice,
// K=365, KI=12) + FM xs3 (sep3 slice, K=40, KI=2). One block per 16-row tile.
// Global reads are row-major coalesced; global writes are FM-contiguous
// (1 KB per wave-store) — both sides stream, no DRAM row thrash.
// ---------------------------------------------------------------------------
__global__ __launch_bounds__(256) void pack_fmt_kernel(
    const float* __restrict__ x, short* __restrict__ xs4,
    short* __restrict__ xs3, int nrows)
{
    __shared__ short sA[16][408];  // combined cols 0..404 (= x_all 16..420)

    int rb = blockIdx.x;
    int tid = threadIdx.x;

    // ---- stage: 16 rows x 405 cols, coalesced ----
    {
        int r = tid >> 4, l16 = tid & 15;
        int grow = rb * 16 + r;
        bool rok = grow < nrows;
        const float* rp = x + (size_t)grow * 441 + 16;
#pragma unroll
        for (int s = 0; s < 7; s++) {
            int c = s * 64 + l16 * 4;
            if (c >= 405) continue;
            if (rok && c + 4 <= 405) {
                f32x4 v = *(const f32x4*)(rp + c);
#pragma unroll
                for (int j = 0; j < 4; j++) sA[r][c + j] = f2b(v[j]);
            } else {
#pragma unroll
                for (int j = 0; j < 4; j++)
                    if (c + j < 405)
                        sA[r][c + j] = rok ? f2b(rp[c + j]) : (short)0;
            }
        }
    }
    __syncthreads();

    // ---- emit: FM fragments, contiguous stores ----
    int wv = tid >> 6, lane = tid & 63;
    int lrow = lane & 15, quad = lane >> 4;

    // xs4: combined cols 40..405 (K=365)
    for (int ki = wv; ki < 12; ki += 4) {
        int kb = ki * 32 + quad * 8;
        short8 v;
        if (kb + 8 <= 365) {
            v = *(const short8*)&sA[lrow][40 + kb];
        } else {
#pragma unroll
            for (int j = 0; j < 8; j++)
                v[j] = (kb + j < 365) ? sA[lrow][40 + kb + j] : (short)0;
        }
        *(short8*)(xs4 + (((size_t)rb * 12 + ki) * 64 + lane) * 8) = v;
    }
    // xs3: combined cols 0..40 (K=40)
    if (wv < 2) {
        int kb = wv * 32 + quad * 8;
        short8 v;
        if (kb + 8 <= 40) {
            v = *(const short8*)&sA[lrow][kb];
        } else {
#pragma unroll
            for (int j = 0; j < 8; j++)
                v[j] = (kb + j < 40) ? sA[lrow][kb + j] : (short)0;
        }
        *(short8*)(xs3 + (((size_t)rb * 2 + wv) * 64 + lane) * 8) = v;
    }
}

// ---------------------------------------------------------------------------
// Batched f32 -> bf16 fragment-major packer for weight tensors.
// ---------------------------------------------------------------------------
struct PackDesc {
    const float* src;
    short* dst;
    int lda, M, K, CT, KI;
};
struct PackArgs {
    PackDesc d[16];
    unsigned long long sz[16];
    int n;
};

__global__ __launch_bounds__(256) void pack_all_kernel(PackArgs pa,
                                                       unsigned long long total)
{
    for (unsigned long long i =
             (unsigned long long)blockIdx.x * blockDim.x + threadIdx.x;
         i < total; i += (unsigned long long)gridDim.x * blockDim.x) {
        unsigned long long off = i;
        int s = 0;
        while (s < pa.n - 1 && off >= pa.sz[s]) { off -= pa.sz[s]; s++; }
        PackDesc D = pa.d[s];
        int j = (int)(off & 7);
        int lane = (int)((off >> 3) & 63);
        unsigned rem = (unsigned)(off >> 9);
        int ct = rem % (unsigned)D.CT;
        int ki = rem / (unsigned)D.CT;
        int r = ct * 16 + (lane & 15);
        int k = ki * 32 + (lane >> 4) * 8 + j;
        float v = (r < D.M && k < D.K) ? D.src[(size_t)r * D.lda + k] : 0.f;
        D.dst[off] = f2b(v);
    }
}

// ---------------------------------------------------------------------------
// Direct-from-global MFMA GEMM (fragment-major operands).
// ---------------------------------------------------------------------------
template <int ACT, int ODT, int CT, int KI, int SCORES>
__global__ __launch_bounds__(256) void dgemm_kernel(
    const short* __restrict__ A,
    const short* __restrict__ W,
    const float* __restrict__ bias,
    void* __restrict__ Cv, int ldc, int nrows, int M,
    const float* __restrict__ a_src, const float* __restrict__ a_dst,
    float* __restrict__ ssrc, float* __restrict__ sdst)
{
    int tid = threadIdx.x;
    int row0 = blockIdx.x * 64;
    int wv = tid >> 6, lane = tid & 63;
    int lrow = lane & 15, quad = lane >> 4;

    const short* Ap = A + ((size_t)((row0 >> 4) + wv) * KI) * 512 + (size_t)lane * 8;
    const short* Wp = W + (size_t)lane * 8;

    short8 areg[KI];
#pragma unroll
    for (int ki = 0; ki < KI; ki++) areg[ki] = *(const short8*)(Ap + (size_t)ki * 512);

    f32x4 acc[CT];
#pragma unroll
    for (int ct = 0; ct < CT; ct++)
#pragma unroll
        for (int i = 0; i < 4; i++) acc[ct][i] = 0.f;

#pragma unroll
    for (int ki = 0; ki < KI; ki++) {
        short8 breg[CT];
#pragma unroll
        for (int ct = 0; ct < CT; ct++)
            breg[ct] = *(const short8*)(Wp + ((size_t)ki * CT + ct) * 512);
#pragma unroll
        for (int ct = 0; ct < CT; ct++)
            acc[ct] = __builtin_amdgcn_mfma_f32_16x16x32_bf16(areg[ki], breg[ct], acc[ct], 0, 0, 0);
    }

    float* Cf = (float*)Cv;
    bf16*  Cb = (bf16*)Cv;
#pragma unroll
    for (int ct = 0; ct < CT; ct++) {
        int gcol = ct * 16 + lrow;
        if (gcol >= M) continue;
        float bv = bias ? bias[gcol] : 0.f;
#pragma unroll
        for (int i = 0; i < 4; i++) {
            int grow = row0 + wv * 16 + quad * 4 + i;
            if (grow >= nrows) continue;
            float v = acc[ct][i] + bv;
            if (ACT == 1) v = fmaxf(v, 0.f);
            if (ACT == 2) v = sigm(v);
            if (ODT == 1) Cb[(size_t)grow * ldc + gcol] = __float2bfloat16(v);
            else          Cf[(size_t)grow * ldc + gcol] = v;
        }
    }

    if (SCORES) {
        float as_c[CT], ad_c[CT];
#pragma unroll
        for (int ct = 0; ct < CT; ct++) {
            int gcol = ct * 16 + lrow;
            as_c[ct] = (gcol < M) ? a_src[gcol] : 0.f;
            ad_c[ct] = (gcol < M) ? a_dst[gcol] : 0.f;
        }
#pragma unroll
        for (int i = 0; i < 4; i++) {
            float ps = 0.f, pd = 0.f;
#pragma unroll
            for (int ct = 0; ct < CT; ct++) {
                ps = fmaf(acc[ct][i], as_c[ct], ps);
                pd = fmaf(acc[ct][i], ad_c[ct], pd);
            }
#pragma unroll
            for (int off = 8; off > 0; off >>= 1) {
                ps += __shfl_down(ps, off);
                pd += __shfl_down(pd, off);
            }
            if (lrow == 0) {
                int grow = row0 + wv * 16 + quad * 4 + i;
                if (grow < nrows) { ssrc[grow] = ps; sdst[grow] = pd; }
            }
        }
    }
}

// ---------------------------------------------------------------------------
// Fused 2-layer MLP branch body: out = relu(W2@sig(W1@a+b1)+b2).
// ADT=0: scalar f32 loads (tiny K). ADT=1: fragment-major bf16 input
// (sequential 1 KB wave-loads). ADT=3: direct vectorized f32x4 fallback.
// W1/W2 fragment-major; output fragment-major.
// ---------------------------------------------------------------------------
template <int ADT, int CT1, int CT2, int KI1>
__device__ __forceinline__ void brmlp_body(
    short* sH,  // [64][CT1*16+8]
    const void* __restrict__ Av, int lda, int aoff,
    const short* __restrict__ W1p, const float* __restrict__ B1,
    const short* __restrict__ W2p, const float* __restrict__ B2,
    short* __restrict__ out, int KIo, int coff, int nrows, int K1)
{
    constexpr int M1 = CT1 * 16;
    constexpr int LDH = M1 + 8;
    constexpr int KI2 = M1 / 32;

    int tid = threadIdx.x;
    int row0 = blockIdx.x * 64;
    int wv = tid >> 6, lane = tid & 63;
    int lrow = lane & 15, quad = lane >> 4;

    // ---- phase 1 ----
    {
        short8 areg[KI1];
        if (ADT == 1) {
            const short* As = (const short*)Av +
                              ((size_t)((row0 >> 4) + wv) * KI1) * 512 + (size_t)lane * 8;
#pragma unroll
            for (int ki = 0; ki < KI1; ki++)
                areg[ki] = *(const short8*)(As + (size_t)ki * 512);
        } else if (ADT == 3) {
            const float* Af = (const float*)Av;
            int arow = row0 + wv * 16 + lrow;
            bool rok = arow < nrows;
            const float* rp = Af + (size_t)arow * lda + aoff;
#pragma unroll
            for (int ki = 0; ki < KI1; ki++) {
                int kb = ki * 32 + quad * 8;
                if (rok && kb + 8 <= K1) {
                    f32x4 a = *(const f32x4*)(rp + kb);
                    f32x4 b = *(const f32x4*)(rp + kb + 4);
#pragma unroll
                    for (int j = 0; j < 4; j++) areg[ki][j] = f2b(a[j]);
#pragma unroll
                    for (int j = 0; j < 4; j++) areg[ki][4 + j] = f2b(b[j]);
                } else if (rok && kb < K1) {
#pragma unroll
                    for (int j = 0; j < 8; j++)
                        areg[ki][j] = (kb + j < K1) ? f2b(rp[kb + j]) : (short)0;
                } else {
#pragma unroll
                    for (int j = 0; j < 8; j++) areg[ki][j] = 0;
                }
            }
        } else {
            const float* Af = (const float*)Av;
            int arow = row0 + wv * 16 + lrow;
            bool rok = arow < nrows;
#pragma unroll
            for (int ki = 0; ki < KI1; ki++)
#pragma unroll
                for (int j = 0; j < 8; j++) {
                    int k = ki * 32 + quad * 8 + j;
                    areg[ki][j] = (rok && k < K1)
                                      ? f2b(Af[(size_t)arow * lda + aoff + k])
                                      : (short)0;
                }
        }

        f32x4 acc[CT1];
#pragma unroll
        for (int ct = 0; ct < CT1; ct++)
#pragma unroll
            for (int i = 0; i < 4; i++) acc[ct][i] = 0.f;

#pragma unroll
        for (int ki = 0; ki < KI1; ki++) {
            short8 breg[CT1];
#pragma unroll
            for (int ct = 0; ct < CT1; ct++)
                breg[ct] = *(const short8*)(W1p + ((size_t)ki * CT1 + ct) * 512 +
                                            (size_t)lane * 8);
#pragma unroll
            for (int ct = 0; ct < CT1; ct++)
                acc[ct] = __builtin_amdgcn_mfma_f32_16x16x32_bf16(areg[ki], breg[ct], acc[ct], 0, 0, 0);
        }
#pragma unroll
        for (int ct = 0; ct < CT1; ct++) {
            int col = ct * 16 + lrow;
            float bv = B1[col];
#pragma unroll
            for (int i = 0; i < 4; i++)
                sH[(wv * 16 + quad * 4 + i) * LDH + col] = f2b(sigm(acc[ct][i] + bv));
        }
    }

    // ---- phase 2 (K2 = M1); per-wave rows, no barrier needed ----
    {
        f32x4 acc[CT2];
#pragma unroll
        for (int ct = 0; ct < CT2; ct++)
#pragma unroll
            for (int i = 0; i < 4; i++) acc[ct][i] = 0.f;

#pragma unroll
        for (int ki = 0; ki < KI2; ki++) {
            short8 a = *(short8*)&sH[(wv * 16 + lrow) * LDH + ki * 32 + quad * 8];
            short8 breg[CT2];
#pragma unroll
            for (int ct = 0; ct < CT2; ct++)
                breg[ct] = *(const short8*)(W2p + ((size_t)ki * CT2 + ct) * 512 +
                                            (size_t)lane * 8);
#pragma unroll
            for (int ct = 0; ct < CT2; ct++)
                acc[ct] = __builtin_amdgcn_mfma_f32_16x16x32_bf16(a, breg[ct], acc[ct], 0, 0, 0);
        }
#pragma unroll
        for (int ct = 0; ct < CT2; ct++) {
            int gcol = ct * 16 + lrow;
            float bv = B2[gcol];
            int c = coff + gcol;
#pragma unroll
            for (int i = 0; i < 4; i++) {
                int grow = row0 + wv * 16 + quad * 4 + i;
                if (grow >= nrows) continue;
                float v = fmaxf(acc[ct][i] + bv, 0.f);
                out[fm_idx(grow, c, KIo)] = f2b(v);
            }
        }
    }
}

template <int ADT, int CT1, int CT2, int KI1>
__global__ __launch_bounds__(256) void brmlp_kernel(
    const void* __restrict__ Av, int lda, int aoff,
    const short* __restrict__ W1p, const float* __restrict__ B1,
    const short* __restrict__ W2p, const float* __restrict__ B2,
    short* __restrict__ out, int KIo, int coff, int nrows, int K1)
{
    __shared__ short sH[64 * (CT1 * 16 + 8)];
    brmlp_body<ADT, CT1, CT2, KI1>(sH, Av, lda, aoff, W1p, B1, W2p, B2,
                                   out, KIo, coff, nrows, K1);
}

// sep1+sep2 fused into one launch (blockIdx.y selects the branch).
__global__ __launch_bounds__(256) void brmlp_pair_kernel(
    const void* __restrict__ Av, int lda,
    const short* __restrict__ W1a, const float* __restrict__ B1a,
    const short* __restrict__ W2a, const float* __restrict__ B2a,
    const short* __restrict__ W1b, const float* __restrict__ B1b,
    const short* __restrict__ W2b, const float* __restrict__ B2b,
    short* __restrict__ out, int KIo, int nrows)
{
    __shared__ short sH[64 * 72];
    if (blockIdx.y == 0)
        brmlp_body<0, 4, 4, 1>(sH, Av, lda, 1, W1a, B1a, W2a, B2a,
                               out, KIo, 0, nrows, 2);
    else
        brmlp_body<0, 4, 4, 1>(sH, Av, lda, 3, W1b, B1b, W2b, B2b,
                               out, KIo, 64, nrows, 13);
}

// ---------------------------------------------------------------------------
// Fused head: concat(gat3_out, lstm_h) -> lin1(relu) -> lin2(relu) -> lin3.
// ---------------------------------------------------------------------------
__global__ __launch_bounds__(256) void head_kernel(
    const short* __restrict__ xgs, const float* __restrict__ x_all,
    const float* __restrict__ wih, const float* __restrict__ bih,
    const float* __restrict__ bhh,
    const short* __restrict__ w1p, const float* __restrict__ b1,
    const short* __restrict__ w2p, const float* __restrict__ b2,
    const short* __restrict__ w3p, const float* __restrict__ b3,
    float* __restrict__ dout, int n)
{
    __shared__ short sW[20][200];
    __shared__ float sT[64][20];
    __shared__ short sH[64][72];
    __shared__ short sH2[64][72];
    __shared__ short sH3[64][72];

    int tid = threadIdx.x;
    int row0 = blockIdx.x * 64;
    int wv = tid >> 6, lane = tid & 63;
    int lrow = lane & 15, quad = lane >> 4;

    short8 axg[2];
#pragma unroll
    for (int ki = 0; ki < 2; ki++)
        axg[ki] = *(const short8*)(xgs + (((size_t)((row0 >> 4) + wv) * 2 + ki) * 64 +
                                          lane) * 8);

    for (int i = tid; i < 20 * 192; i += 256) {
        int k = i / 192, j = i % 192;
        int gate = j >> 6, jj = j & 63;
        int srow = (gate == 0) ? jj : (gate == 1 ? 128 + jj : 192 + jj);
        sW[k][j] = f2b(wih[srow * 20 + k]);
    }
    for (int i = tid; i < 64 * 20; i += 256) {
        int r = i / 20, k = i % 20;
        int grow = row0 + r;
        sT[r][k] = (grow < n) ? x_all[(size_t)grow * 441 + 421 + k] : 0.f;
    }
    __syncthreads();

    for (int p = 0; p < 16; p++) {
        int idx = p * 256 + tid;
        int r = idx >> 6, j = idx & 63;
        float gi = 0.f, gg = 0.f, go = 0.f;
#pragma unroll
        for (int k = 0; k < 20; k++) {
            float t = sT[r][k];
            gi = fmaf(t, b2f_s((unsigned short)sW[k][j]), gi);
            gg = fmaf(t, b2f_s((unsigned short)sW[k][64 + j]), gg);
            go = fmaf(t, b2f_s((unsigned short)sW[k][128 + j]), go);
        }
        gi += bih[j] + bhh[j];
        gg += bih[128 + j] + bhh[128 + j];
        go += bih[192 + j] + bhh[192 + j];
        float c = sigm(gi) * tanhf(gg);
        float h = sigm(go) * tanhf(c);
        sH[r][j] = f2b(h);
    }
    __syncthreads();

    f32x4 acc[4];
#pragma unroll
    for (int ct = 0; ct < 4; ct++)
#pragma unroll
        for (int i = 0; i < 4; i++) acc[ct][i] = 0.f;
#pragma unroll
    for (int ki = 0; ki < 4; ki++) {
        short8 a = (ki < 2) ? axg[ki]
                            : *(short8*)&sH[wv * 16 + lrow][(ki - 2) * 32 + quad * 8];
        short8 breg[4];
#pragma unroll
        for (int ct = 0; ct < 4; ct++)
            breg[ct] = *(const short8*)(w1p + ((size_t)ki * 4 + ct) * 512 +
                                        (size_t)lane * 8);
#pragma unroll
        for (int ct = 0; ct < 4; ct++)
            acc[ct] = __builtin_amdgcn_mfma_f32_16x16x32_bf16(a, breg[ct], acc[ct], 0, 0, 0);
    }
#pragma unroll
    for (int ct = 0; ct < 4; ct++) {
        int col = ct * 16 + lrow;
        float bv = b1[col];
#pragma unroll
        for (int i = 0; i < 4; i++)
            sH2[wv * 16 + quad * 4 + i][col] = f2b(fmaxf(acc[ct][i] + bv, 0.f));
    }

#pragma unroll
    for (int ct = 0; ct < 4; ct++)
#pragma unroll
        for (int i = 0; i < 4; i++) acc[ct][i] = 0.f;
#pragma unroll
    for (int ki = 0; ki < 2; ki++) {
        short8 a = *(short8*)&sH2[wv * 16 + lrow][ki * 32 + quad * 8];
        short8 breg[4];
#pragma unroll
        for (int ct = 0; ct < 4; ct++)
            breg[ct] = *(const short8*)(w2p + ((size_t)ki * 4 + ct) * 512 +
                                        (size_t)lane * 8);
#pragma unroll
        for (int ct = 0; ct < 4; ct++)
            acc[ct] = __builtin_amdgcn_mfma_f32_16x16x32_bf16(a, breg[ct], acc[ct], 0, 0, 0);
    }
#pragma unroll
    for (int ct = 0; ct < 4; ct++) {
        int col = ct * 16 + lrow;
        float bv = b2[col];
#pragma unroll
        for (int i = 0; i < 4; i++)
            sH3[wv * 16 + quad * 4 + i][col] = f2b(fmaxf(acc[ct][i] + bv, 0.f));
    }

#pragma unroll
    for (int ct = 0; ct < 4; ct++)
#pragma unroll
        for (int i = 0; i < 4; i++) acc[ct][i] = 0.f;
#pragma unroll
    for (int ki = 0; ki < 2; ki++) {
        short8 a = *(short8*)&sH3[wv * 16 + lrow][ki * 32 + quad * 8];
        short8 breg[4];
#pragma unroll
        for (int ct = 0; ct < 4; ct++)
            breg[ct] = *(const short8*)(w3p + ((size_t)ki * 4 + ct) * 512 +
                                        (size_t)lane * 8);
#pragma unroll
        for (int ct = 0; ct < 4; ct++)
            acc[ct] = __builtin_amdgcn_mfma_f32_16x16x32_bf16(a, breg[ct], acc[ct], 0, 0, 0);
    }
#pragma unroll
    for (int ct = 0; ct < 4; ct++) {
        int gcol = ct * 16 + lrow;
        if (gcol >= 56) continue;
        float bv = b3[gcol];
#pragma unroll
        for (int i = 0; i < 4; i++) {
            int grow = row0 + wv * 16 + quad * 4 + i;
            if (grow >= n) continue;
            dout[(size_t)grow * 56 + gcol] = acc[ct][i] + bv;
        }
    }
}

// ---------------------------------------------------------------------------
// Fused GAT aggregation, 8-deep gather unroll. Output fragment-major.
// ---------------------------------------------------------------------------
template <int FPL, int KIo>
__global__ __launch_bounds__(256) void gat_fused_kernel(
    const bf16* __restrict__ hw, const int* __restrict__ rowptr,
    const int* __restrict__ colidx, const float* __restrict__ ss,
    const float* __restrict__ sd, const float* __restrict__ bias,
    short* __restrict__ out, int n, int F)
{
    int wv = threadIdx.x >> 6, lane = threadIdx.x & 63;
    int node = blockIdx.x * 4 + wv;
    if (node >= n) return;
    const unsigned short* hwu = (const unsigned short*)hw;
    float sdn = sd[node];
    float wself = expf(lrelu(ss[node] + sdn));
    float a0, a1 = 0.f;
    if (FPL == 2) {
        unsigned u = *(const unsigned*)(hwu + (size_t)node * F + 2 * lane);
        a0 = wself * lo_bf(u);
        a1 = wself * hi_bf(u);
    } else {
        a0 = wself * b2f_s(hwu[(size_t)node * F + lane]);
    }
    int e0 = rowptr[node];
    int deg = rowptr[node + 1] - e0;
    float den_l = 0.f;
    for (int c0 = 0; c0 < deg; c0 += 64) {
        int mye = c0 + lane;
        int s = 0;
        float w = 0.f;
        if (mye < deg) {
            s = colidx[e0 + mye];
            w = expf(lrelu(ss[s] + sdn));
        }
        den_l += w;
        int cnt = min(64, deg - c0);
        int j = 0;
        for (; j + 7 < cnt; j += 8) {
            int sx[8];
            float wx[8];
#pragma unroll
            for (int q = 0; q < 8; q++) {
                sx[q] = __shfl(s, j + q);
                wx[q] = __shfl(w, j + q);
            }
            if (FPL == 2) {
                unsigned ux[8];
#pragma unroll
                for (int q = 0; q < 8; q++)
                    ux[q] = *(const unsigned*)(hwu + (size_t)sx[q] * F + 2 * lane);
#pragma unroll
                for (int q = 0; q < 8; q++) {
                    a0 = fmaf(wx[q], lo_bf(ux[q]), a0);
                    a1 = fmaf(wx[q], hi_bf(ux[q]), a1);
                }
            } else {
                float hx[8];
#pragma unroll
                for (int q = 0; q < 8; q++)
                    hx[q] = b2f_s(hwu[(size_t)sx[q] * F + lane]);
#pragma unroll
                for (int q = 0; q < 8; q++) a0 = fmaf(wx[q], hx[q], a0);
            }
        }
        for (; j + 3 < cnt; j += 4) {
            int s0 = __shfl(s, j), s1 = __shfl(s, j + 1);
            int s2 = __shfl(s, j + 2), s3 = __shfl(s, j + 3);
            float w0 = __shfl(w, j), w1v = __shfl(w, j + 1);
            float w2v = __shfl(w, j + 2), w3v = __shfl(w, j + 3);
            if (FPL == 2) {
                unsigned u0 = *(const unsigned*)(hwu + (size_t)s0 * F + 2 * lane);
                unsigned u1 = *(const unsigned*)(hwu + (size_t)s1 * F + 2 * lane);
                unsigned u2 = *(const unsigned*)(hwu + (size_t)s2 * F + 2 * lane);
                unsigned u3 = *(const unsigned*)(hwu + (size_t)s3 * F + 2 * lane);
                a0 = fmaf(w0, lo_bf(u0), a0);  a1 = fmaf(w0, hi_bf(u0), a1);
                a0 = fmaf(w1v, lo_bf(u1), a0); a1 = fmaf(w1v, hi_bf(u1), a1);
                a0 = fmaf(w2v, lo_bf(u2), a0); a1 = fmaf(w2v, hi_bf(u2), a1);
                a0 = fmaf(w3v, lo_bf(u3), a0); a1 = fmaf(w3v, hi_bf(u3), a1);
            } else {
                float h0 = b2f_s(hwu[(size_t)s0 * F + lane]);
                float h1 = b2f_s(hwu[(size_t)s1 * F + lane]);
                float h2 = b2f_s(hwu[(size_t)s2 * F + lane]);
                float h3 = b2f_s(hwu[(size_t)s3 * F + lane]);
                a0 = fmaf(w0, h0, a0);
                a0 = fmaf(w1v, h1, a0);
                a0 = fmaf(w2v, h2, a0);
                a0 = fmaf(w3v, h3, a0);
            }
        }
        for (; j < cnt; j++) {
            int s0 = __shfl(s, j);
            float w0 = __shfl(w, j);
            if (FPL == 2) {
                unsigned u0 = *(const unsigned*)(hwu + (size_t)s0 * F + 2 * lane);
                a0 = fmaf(w0, lo_bf(u0), a0);
                a1 = fmaf(w0, hi_bf(u0), a1);
            } else {
                a0 = fmaf(w0, b2f_s(hwu[(size_t)s0 * F + lane]), a0);
            }
        }
    }
#pragma unroll
    for (int off = 32; off > 0; off >>= 1) den_l += __shfl_xor(den_l, off);
    float inv = 1.f / (den_l + wself);
    int rb = node >> 4, nr = node & 15;
    if (FPL == 2) {
        float v0 = fmaxf(a0 * inv + bias[2 * lane], 0.f);
        float v1 = fmaxf(a1 * inv + bias[2 * lane + 1], 0.f);
        size_t uidx = ((size_t)rb * KIo + (lane >> 4)) * 256 +
                      (size_t)((lane >> 2) & 3) * 64 + nr * 4 + (lane & 3);
        ((unsigned*)out)[uidx] = pack_bf(v0, v1);
    } else {
        float v0 = fmaxf(a0 * inv + bias[lane], 0.f);
        size_t sidx = ((size_t)rb * KIo + (lane >> 5)) * 512 +
                      (size_t)((lane >> 3) & 3) * 128 + nr * 8 + (lane & 7);
        out[sidx] = f2b(v0);
    }
}

// ---------------------------------------------------------------------------
// Bucketed CSR build (write-amp-free):
//   bhist -> bscan -> bpart (bucket-partitioned pairs) -> bcsr (one block
//   per bucket: LDS per-node count + scan + scatter within a private window).
// ---------------------------------------------------------------------------
__global__ __launch_bounds__(256) void bhist_kernel(const int* __restrict__ dst,
                                                    int* __restrict__ bcnt, int e)
{
    __shared__ int l[NB];
    for (int i = threadIdx.x; i < NB; i += 256) l[i] = 0;
    __syncthreads();
    for (int i = blockIdx.x * blockDim.x + threadIdx.x; i < e;
         i += gridDim.x * blockDim.x)
        atomicAdd(&l[dst[i] >> 8], 1);
    __syncthreads();
    for (int i = threadIdx.x; i < NB; i += 256)
        if (l[i]) atomicAdd(&bcnt[i], l[i]);
}

__global__ __launch_bounds__(256) void bscan_kernel(
    const int* __restrict__ bcnt, int* __restrict__ boff,
    int* __restrict__ bcur, int* __restrict__ rowptr, int n, int e)
{
    __shared__ int tmp[256];
    int tid = threadIdx.x;
    int v = (tid < NB) ? bcnt[tid] : 0;
    tmp[tid] = v;
    __syncthreads();
    for (int off = 1; off < 256; off <<= 1) {
        int t = (tid >= off) ? tmp[tid - off] : 0;
        __syncthreads();
        tmp[tid] += t;
        __syncthreads();
    }
    int excl = tmp[tid] - v;
    if (tid < NB) { boff[tid] = excl; bcur[tid] = excl; }
    if (tid == 0) { boff[NB] = e; rowptr[n] = e; }
}

__global__ __launch_bounds__(256) void bpart_kernel(
    const int* __restrict__ src, const int* __restrict__ dst,
    int* __restrict__ bcur, int2* __restrict__ pairs, int e)
{
    __shared__ int lcnt[NB];
    __shared__ int lbase[NB];
    const int TILE = 2048;
    for (long long t0 = (long long)blockIdx.x * TILE; t0 < e;
         t0 += (long long)gridDim.x * TILE) {
        for (int i = threadIdx.x; i < NB; i += 256) lcnt[i] = 0;
        __syncthreads();
        int rank[8], bb[8], sv[8], dv[8];
#pragma unroll
        for (int k = 0; k < 8; k++) {
            int i = (int)t0 + k * 256 + threadIdx.x;
            bb[k] = -1;
            if (i < e) {
                int d = dst[i];
                sv[k] = src[i];
                dv[k] = d;
                bb[k] = d >> 8;
                rank[k] = atomicAdd(&lcnt[bb[k]], 1);
            }
        }
        __syncthreads();
        for (int i = threadIdx.x; i < NB; i += 256)
            lbase[i] = lcnt[i] ? atomicAdd(&bcur[i], lcnt[i]) : 0;
        __syncthreads();
#pragma unroll
        for (int k = 0; k < 8; k++)
            if (bb[k] >= 0)
                pairs[(size_t)lbase[bb[k]] + rank[k]] = make_int2(sv[k], dv[k]);
        __syncthreads();
    }
}

__global__ __launch_bounds__(256) void bcsr_kernel(
    const int2* __restrict__ pairs, const int* __restrict__ boff,
    int* __restrict__ rowptr, int* __restrict__ colidx, int n)
{
    __shared__ int ncnt[256];
    __shared__ int tmp[256];
    int tid = threadIdx.x, b = blockIdx.x;
    int base = boff[b], end = boff[b + 1];
    ncnt[tid] = 0;
    __syncthreads();
    for (int i = base + tid; i < end; i += 256)
        atomicAdd(&ncnt[pairs[i].y & 255], 1);
    __syncthreads();
    int v = ncnt[tid];
    tmp[tid] = v;
    __syncthreads();
    for (int off = 1; off < 256; off <<= 1) {
        int t = (tid >= off) ? tmp[tid - off] : 0;
        __syncthreads();
        tmp[tid] += t;
        __syncthreads();
    }
    int excl = base + tmp[tid] - v;
    int node = (b << 8) + tid;
    if (node < n) rowptr[node] = excl;
    __syncthreads();
    ncnt[tid] = excl;
    __syncthreads();
    for (int i = base + tid; i < end; i += 256) {
        int2 p = pairs[i];
        int pos = atomicAdd(&ncnt[p.y & 255], 1);
        colidx[pos] = p.x;
    }
}

// ---------------------------------------------------------------------------
// Legacy CSR build (fallback if workspace too small for the pairs buffer).
// ---------------------------------------------------------------------------
__global__ void count_kernel(const int* __restrict__ dst, int* __restrict__ cnt,
                             int e)
{
    for (int i = blockIdx.x * blockDim.x + threadIdx.x; i < e;
         i += gridDim.x * blockDim.x)
        atomicAdd(cnt + dst[i], 1);
}

#define SCAN_BLOCKS 256

__global__ __launch_bounds__(256) void scan_local_kernel(
    const int* __restrict__ cnt, int* __restrict__ rowptr,
    int* __restrict__ bsum, int n, int chunk)
{
    __shared__ int tmp[256];
    int b = blockIdx.x, tid = threadIdx.x;
    int i = b * chunk + tid;
    int v = (tid < chunk && i < n) ? cnt[i] : 0;
    tmp[tid] = v;
    __syncthreads();
    for (int off = 1; off < 256; off <<= 1) {
        int t = (tid >= off) ? tmp[tid - off] : 0;
        __syncthreads();
        tmp[tid] += t;
        __syncthreads();
    }
    if (tid < chunk && i < n) rowptr[i] = tmp[tid] - v;
    if (tid == 255) bsum[b] = tmp[255];
}

__global__ __launch_bounds__(256) void scan_bsums_kernel(
    int* __restrict__ bsum, int* __restrict__ rowptr, int n)
{
    __shared__ int tmp[256];
    int tid = threadIdx.x;
    int v = bsum[tid];
    tmp[tid] = v;
    __syncthreads();
    for (int off = 1; off < 256; off <<= 1) {
        int t = (tid >= off) ? tmp[tid - off] : 0;
        __syncthreads();
        tmp[tid] += t;
        __syncthreads();
    }
    bsum[tid] = tmp[tid] - v;
    if (tid == 255) rowptr[n] = tmp[255];
}

__global__ __launch_bounds__(256) void scan_add_kernel(
    int* __restrict__ rowptr, int* __restrict__ nextp,
    const int* __restrict__ bsum, int n, int chunk)
{
    int b = blockIdx.x, tid = threadIdx.x;
    int i = b * chunk + tid;
    if (tid < chunk && i < n) {
        int v = rowptr[i] + bsum[b];
        rowptr[i] = v;
        nextp[i] = v;
    }
}

__global__ void fill_kernel(const int* __restrict__ src,
                            const int* __restrict__ dst,
                            int* __restrict__ nextp, int* __restrict__ colidx,
                            int e)
{
    for (int i = blockIdx.x * blockDim.x + threadIdx.x; i < e;
         i += gridDim.x * blockDim.x) {
        int pos = atomicAdd(nextp + dst[i], 1);
        colidx[pos] = src[i];
    }
}

// ---------------------------------------------------------------------------
extern "C" void kernel_launch(void* const* d_in, const int* in_sizes, int n_in,
                              void* d_out, int out_size, void* d_ws,
                              size_t ws_size, hipStream_t stream)
{
    const int N = N_NODES;
    const int E = N_EDGES;

    const float* x_all = (const float*)d_in[0];
    const int* edges = (const int*)d_in[1];
    const int* e_src = edges;
    const int* e_dst = edges + E;

    const float* sep1_w = (const float*)d_in[2];  const float* sep1_b = (const float*)d_in[3];
    const float* sep2_w = (const float*)d_in[4];  const float* sep2_b = (const float*)d_in[5];
    const float* sep3_w = (const float*)d_in[6];  const float* sep3_b = (const float*)d_in[7];
    const float* sep4_w = (const float*)d_in[8];  const float* sep4_b = (const float*)d_in[9];
    const float* sep5_w = (const float*)d_in[10]; const float* sep5_b = (const float*)d_in[11];
    const float* sep6_w = (const float*)d_in[12]; const float* sep6_b = (const float*)d_in[13];
    const float* sep7_w = (const float*)d_in[14]; const float* sep7_b = (const float*)d_in[15];
    const float* sep8_w = (const float*)d_in[16]; const float* sep8_b = (const float*)d_in[17];
    const float* conv1_w = (const float*)d_in[18];
    const float* conv1_as = (const float*)d_in[19];
    const float* conv1_ad = (const float*)d_in[20];
    const float* conv1_b = (const float*)d_in[21];
    const float* conv2_w = (const float*)d_in[22];
    const float* conv2_as = (const float*)d_in[23];
    const float* conv2_ad = (const float*)d_in[24];
    const float* conv2_b = (const float*)d_in[25];
    const float* conv3_w = (const float*)d_in[26];
    const float* conv3_as = (const float*)d_in[27];
    const float* conv3_ad = (const float*)d_in[28];
    const float* conv3_b = (const float*)d_in[29];
    const float* lstm_wih = (const float*)d_in[30];
    const float* lstm_bih = (const float*)d_in[32];
    const float* lstm_bhh = (const float*)d_in[33];
    const float* lin1_w = (const float*)d_in[34]; const float* lin1_b = (const float*)d_in[35];
    const float* lin2_w = (const float*)d_in[36]; const float* lin2_b = (const float*)d_in[37];
    const float* lin3_w = (const float*)d_in[38]; const float* lin3_b = (const float*)d_in[39];

    char* ws = (char*)d_ws;
    size_t off = 0;
    auto alloc = [&](size_t bytes) {
        void* p = ws + off;
        off += (bytes + 255) & ~(size_t)255;
        return p;
    };
    short* x0 = (short*)alloc((size_t)NP * 384 * 2);  // FM concat / C ping / xg
    short* Bb = (short*)alloc((size_t)NP * 128 * 2);  // hw buffer (row-major)
    float* ssrc = (float*)alloc((size_t)N * 4);
    float* sdst = (float*)alloc((size_t)N * 4);
    int* rowptr = (int*)alloc((size_t)(N + 1) * 4);
    int* nextp  = (int*)alloc((size_t)N * 4);
    int* cnt    = (int*)alloc((size_t)N * 4);
    int* bsum   = (int*)alloc((size_t)SCAN_BLOCKS * 4);
    int* colidx = (int*)alloc((size_t)E * 4);
    int* bcnt   = (int*)alloc((size_t)NB * 4);
    int* boff   = (int*)alloc((size_t)(NB + 1) * 4);
    int* bcur   = (int*)alloc((size_t)NB * 4);

    short* conv1p = (short*)alloc((size_t)128 * 384 * 2);
    short* conv2p = (short*)alloc((size_t)128 * 128 * 2);
    short* conv3p = (short*)alloc((size_t)64 * 128 * 2);
    short* sep1p  = (short*)alloc((size_t)64 * 32 * 2);
    short* sep2p  = (short*)alloc((size_t)64 * 32 * 2);
    short* sep3p  = (short*)alloc((size_t)128 * 64 * 2);
    short* sep4p  = (short*)alloc((size_t)128 * 384 * 2);
    short* sep5p  = (short*)alloc((size_t)64 * 64 * 2);
    short* sep6p  = (short*)alloc((size_t)64 * 64 * 2);
    short* sep7p  = (short*)alloc((size_t)128 * 128 * 2);
    short* sep8p  = (short*)alloc((size_t)128 * 128 * 2);
    short* lin1p  = (short*)alloc((size_t)64 * 128 * 2);
    short* lin2p  = (short*)alloc((size_t)64 * 64 * 2);
    short* lin3p  = (short*)alloc((size_t)64 * 64 * 2);

    size_t need_pairs = off + (size_t)E * 8 + 1024;
    bool binfill = ws_size >= need_pairs;
    int2* pairs = binfill ? (int2*)alloc((size_t)E * 8) : nullptr;

    size_t need_xs = off + (size_t)NP * 64 * 2 + (size_t)NP * 384 * 2 + 1024;
    bool packx = ws_size >= need_xs;
    short* xs3 = packx ? (short*)alloc((size_t)NP * 64 * 2) : nullptr;
    short* xs4 = packx ? (short*)alloc((size_t)NP * 384 * 2) : nullptr;

    short* C  = x0;   // GAT ping buffer (N,128) FM KIo=4
    short* xg = x0;   // GAT3 out (N,64) FM KIo=2

    dim3 blk(256);
    int gx = NP / 64;  // 782
    int nb4 = (N + 3) / 4;

    // --- CSR build ---
    if (binfill) {
        hipMemsetAsync(bcnt, 0, (size_t)NB * 4, stream);
        bhist_kernel<<<1024, 256, 0, stream>>>(e_dst, bcnt, E);
        bscan_kernel<<<1, 256, 0, stream>>>(bcnt, boff, bcur, rowptr, N, E);
        bpart_kernel<<<(E + 2047) / 2048, 256, 0, stream>>>(e_src, e_dst, bcur,
                                                            pairs, E);
        bcsr_kernel<<<NB, 256, 0, stream>>>(pairs, boff, rowptr, colidx, N);
    } else {
        int chunk = (N + SCAN_BLOCKS - 1) / SCAN_BLOCKS;
        hipMemsetAsync(cnt, 0, (size_t)N * 4, stream);
        count_kernel<<<1024, 256, 0, stream>>>(e_dst, cnt, E);
        scan_local_kernel<<<SCAN_BLOCKS, 256, 0, stream>>>(cnt, rowptr, bsum, N, chunk);
        scan_bsums_kernel<<<1, 256, 0, stream>>>(bsum, rowptr, N);
        scan_add_kernel<<<SCAN_BLOCKS, 256, 0, stream>>>(rowptr, nextp, bsum, N, chunk);
        fill_kernel<<<1024, 256, 0, stream>>>(e_src, e_dst, nextp, colidx, E);
    }

    // --- LDS-tiled transpose pack: x_all -> FM xs4/xs3 (both sides stream) ---
    if (packx)
        pack_fmt_kernel<<<RB16, blk, 0, stream>>>(x_all, xs4, xs3, N);

    // --- pack weights (fragment-major) ---
    {
        PackArgs pa{};
        unsigned long long total = 0;
        int np = 0;
        auto addp = [&](const float* src, short* dst, int lda, int M, int K,
                        int CT, int KI) {
            pa.d[np].src = src; pa.d[np].dst = dst; pa.d[np].lda = lda;
            pa.d[np].M = M; pa.d[np].K = K; pa.d[np].CT = CT; pa.d[np].KI = KI;
            pa.sz[np] = (unsigned long long)CT * KI * 512;
            total += pa.sz[np];
            np++;
        };
        addp(conv1_w, conv1p, 384, 128, 384, 8, 12);
        addp(sep4_w, sep4p, 365, 128, 365, 8, 12);
        addp(conv2_w, conv2p, 128, 128, 128, 8, 4);
        addp(sep7_w, sep7p, 128, 128, 128, 8, 4);
        addp(sep8_w, sep8p, 128, 128, 128, 8, 4);
        addp(conv3_w, conv3p, 128, 64, 128, 4, 4);
        addp(lin1_w, lin1p, 128, 64, 128, 4, 4);
        addp(sep3_w, sep3p, 40, 128, 40, 8, 2);
        addp(sep5_w, sep5p, 64, 64, 64, 4, 2);
        addp(sep6_w, sep6p, 64, 64, 64, 4, 2);
        addp(lin2_w, lin2p, 64, 64, 64, 4, 2);
        addp(lin3_w, lin3p, 64, 56, 64, 4, 2);
        addp(sep1_w, sep1p, 2, 64, 2, 4, 1);
        addp(sep2_w, sep2p, 13, 64, 13, 4, 1);
        pa.n = np;
        pack_all_kernel<<<512, 256, 0, stream>>>(pa, total);
    }

    // --- four fused MLP branches -> x0 (N,384) bf16, fragment-major ---
    brmlp_pair_kernel<<<dim3(gx, 2), blk, 0, stream>>>(
        x_all, 441, sep1p, sep1_b, sep5p, sep5_b,
        sep2p, sep2_b, sep6p, sep6_b, x0, 12, N);
    if (packx) {
        brmlp_kernel<1, 8, 8, 2><<<gx, blk, 0, stream>>>(
            xs3, 64, 0, sep3p, sep3_b, sep7p, sep7_b, x0, 12, 128, N, 64);
        brmlp_kernel<1, 8, 8, 12><<<gx, blk, 0, stream>>>(
            xs4, 384, 0, sep4p, sep4_b, sep8p, sep8_b, x0, 12, 256, N, 384);
    } else {
        brmlp_kernel<3, 8, 8, 2><<<gx, blk, 0, stream>>>(
            x_all, 441, 16, sep3p, sep3_b, sep7p, sep7_b, x0, 12, 128, N, 40);
        brmlp_kernel<3, 8, 8, 12><<<gx, blk, 0, stream>>>(
            x_all, 441, 56, sep4p, sep4_b, sep8p, sep8_b, x0, 12, 256, N, 365);
    }

    // --- GAT layers (scores fused into GEMM epilogue; FM operand loads) ---
    dgemm_kernel<0, 1, 8, 12, 1><<<gx, blk, 0, stream>>>(
        x0, conv1p, nullptr, Bb, 128, N, 128,
        conv1_as, conv1_ad, ssrc, sdst);
    gat_fused_kernel<2, 4><<<nb4, 256, 0, stream>>>(
        (const bf16*)Bb, rowptr, colidx, ssrc, sdst, conv1_b, C, N, 128);

    dgemm_kernel<0, 1, 8, 4, 1><<<gx, blk, 0, stream>>>(
        C, conv2p, nullptr, Bb, 128, N, 128,
        conv2_as, conv2_ad, ssrc, sdst);
    gat_fused_kernel<2, 4><<<nb4, 256, 0, stream>>>(
        (const bf16*)Bb, rowptr, colidx, ssrc, sdst, conv2_b, C, N, 128);

    dgemm_kernel<0, 1, 4, 4, 1><<<gx, blk, 0, stream>>>(
        C, conv3p, nullptr, Bb, 64, N, 64,
        conv3_as, conv3_ad, ssrc, sdst);
    gat_fused_kernel<1, 2><<<nb4, 256, 0, stream>>>(
        (const bf16*)Bb, rowptr, colidx, ssrc, sdst, conv3_b, xg, N, 64);

    // --- fused head: lstm + lin1 + lin2 + lin3 ---
    head_kernel<<<gx, blk, 0, stream>>>(
        xg, x_all, lstm_wih, lstm_bih, lstm_bhh,
        lin1p, lin1_b, lin2p, lin2_b, lin3p, lin3_b,
        (float*)d_out, N);
}

// Round 12
// 497.630 us; speedup vs baseline: 1.0634x; 1.0250x over previous
//
#include <hip/hip_runtime.h>
#include <hip/hip_bf16.h>
#include <math.h>

#define N_NODES 50000
#define N_EDGES 800000
#define NP 50048   // N rounded up to 64
#define RB16 (NP / 16)  // 3128 row-blocks of 16
#define NB 196     // CSR buckets: (N + 255) >> 8

typedef __hip_bfloat16 bf16;
typedef __attribute__((ext_vector_type(8))) short short8;
typedef __attribute__((ext_vector_type(4))) float f32x4;

__device__ __forceinline__ float lrelu(float x) { return x > 0.f ? x : 0.2f * x; }

__device__ __forceinline__ short f2b(float v) {
    bf16 h = __float2bfloat16(v);
    return *reinterpret_cast<short*>(&h);
}
__device__ __forceinline__ float lo_bf(unsigned u) { return __uint_as_float(u << 16); }
__device__ __forceinline__ float hi_bf(unsigned u) { return __uint_as_float(u & 0xFFFF0000u); }
__device__ __forceinline__ float b2f_s(unsigned short s) {
    return __uint_as_float(((unsigned)s) << 16);
}
__device__ __forceinline__ unsigned pack_bf(float v0, float v1) {
    unsigned a = (unsigned)(unsigned short)f2b(v0);
    unsigned b = (unsigned)(unsigned short)f2b(v1);
    return a | (b << 16);
}
__device__ __forceinline__ float sigm(float x) { return 1.f / (1.f + expf(-x)); }

// Fragment-major ("FM") layout for MFMA operands:
//   element (row, col) of an (Mp x Kp) operand lives at
//   ((row>>4)*KI + (col>>5))*512 + ((col>>3)&3)*128 + (row&15)*8 + (col&7)
__device__ __forceinline__ size_t fm_idx(int row, int c, int KIo) {
    return ((size_t)(row >> 4) * KIo + (c >> 5)) * 512 +
           (size_t)((c >> 3) & 3) * 128 + (size_t)(row & 15) * 8 + (c & 7);
}

// ---------------------------------------------------------------------------
// Weight packer descriptors (f32 row-major -> bf16 fragment-major).
// ---------------------------------------------------------------------------
struct PackDesc {
    const float* src;
    short* dst;
    int lda, M, K, CT, KI;
};
struct PackArgs {
    PackDesc d[16];
    unsigned long long sz[16];
    int n;
};

__device__ __forceinline__ void pack_all_body(const PackArgs& pa,
                                              unsigned long long total,
                                              long long start, long long stride)
{
    for (unsigned long long i = start; i < total; i += stride) {
        unsigned long long off = i;
        int s = 0;
        while (s < pa.n - 1 && off >= pa.sz[s]) { off -= pa.sz[s]; s++; }
        PackDesc D = pa.d[s];
        int j = (int)(off & 7);
        int lane = (int)((off >> 3) & 63);
        unsigned rem = (unsigned)(off >> 9);
        int ct = rem % (unsigned)D.CT;
        int ki = rem / (unsigned)D.CT;
        int r = ct * 16 + (lane & 15);
        int k = ki * 32 + (lane >> 4) * 8 + j;
        float v = (r < D.M && k < D.K) ? D.src[(size_t)r * D.lda + k] : 0.f;
        D.dst[off] = f2b(v);
    }
}

__global__ __launch_bounds__(256) void pack_all_kernel(PackArgs pa,
                                                       unsigned long long total)
{
    pack_all_body(pa, total,
                  (long long)blockIdx.x * blockDim.x + threadIdx.x,
                  (long long)gridDim.x * blockDim.x);
}

// ---------------------------------------------------------------------------
// Fused packer: blocks [0, RB16) run the LDS-tiled transposing x_all packer
// (row-major coalesced reads -> FM-contiguous xs4/xs3 writes); remaining
// blocks pack the weight tensors. One launch instead of two.
// ---------------------------------------------------------------------------
__global__ __launch_bounds__(256) void pack_misc_kernel(
    const float* __restrict__ x, short* __restrict__ xs4,
    short* __restrict__ xs3, int nrows,
    PackArgs pa, unsigned long long total, int fmtBlocks)
{
    __shared__ short sA[16][408];  // combined cols 0..404 (= x_all 16..420)
    int tid = threadIdx.x;

    if ((int)blockIdx.x >= fmtBlocks) {
        int wb = blockIdx.x - fmtBlocks;
        int wg = gridDim.x - fmtBlocks;
        pack_all_body(pa, total, (long long)wb * 256 + tid,
                      (long long)wg * 256);
        return;
    }

    int rb = blockIdx.x;

    // ---- stage: 16 rows x 405 cols, coalesced ----
    {
        int r = tid >> 4, l16 = tid & 15;
        int grow = rb * 16 + r;
        bool rok = grow < nrows;
        const float* rp = x + (size_t)grow * 441 + 16;
#pragma unroll
        for (int s = 0; s < 7; s++) {
            int c = s * 64 + l16 * 4;
            if (c >= 405) continue;
            if (rok && c + 4 <= 405) {
                f32x4 v = *(const f32x4*)(rp + c);
#pragma unroll
                for (int j = 0; j < 4; j++) sA[r][c + j] = f2b(v[j]);
            } else {
#pragma unroll
                for (int j = 0; j < 4; j++)
                    if (c + j < 405)
                        sA[r][c + j] = rok ? f2b(rp[c + j]) : (short)0;
            }
        }
    }
    __syncthreads();

    // ---- emit: FM fragments, contiguous stores ----
    int wv = tid >> 6, lane = tid & 63;
    int lrow = lane & 15, quad = lane >> 4;

    // xs4: combined cols 40..405 (K=365)
    for (int ki = wv; ki < 12; ki += 4) {
        int kb = ki * 32 + quad * 8;
        short8 v;
        if (kb + 8 <= 365) {
            v = *(const short8*)&sA[lrow][40 + kb];
        } else {
#pragma unroll
            for (int j = 0; j < 8; j++)
                v[j] = (kb + j < 365) ? sA[lrow][40 + kb + j] : (short)0;
        }
        *(short8*)(xs4 + (((size_t)rb * 12 + ki) * 64 + lane) * 8) = v;
    }
    // xs3: combined cols 0..40 (K=40)
    if (wv < 2) {
        int kb = wv * 32 + quad * 8;
        short8 v;
        if (kb + 8 <= 40) {
            v = *(const short8*)&sA[lrow][kb];
        } else {
#pragma unroll
            for (int j = 0; j < 8; j++)
                v[j] = (kb + j < 40) ? sA[lrow][kb + j] : (short)0;
        }
        *(short8*)(xs3 + (((size_t)rb * 2 + wv) * 64 + lane) * 8) = v;
    }
}

// ---------------------------------------------------------------------------
// Direct-from-global MFMA GEMM (fragment-major operands).
// ---------------------------------------------------------------------------
template <int ACT, int ODT, int CT, int KI, int SCORES>
__global__ __launch_bounds__(256) void dgemm_kernel(
    const short* __restrict__ A,
    const short* __restrict__ W,
    const float* __restrict__ bias,
    void* __restrict__ Cv, int ldc, int nrows, int M,
    const float* __restrict__ a_src, const float* __restrict__ a_dst,
    float* __restrict__ ssrc, float* __restrict__ sdst)
{
    int tid = threadIdx.x;
    int row0 = blockIdx.x * 64;
    int wv = tid >> 6, lane = tid & 63;
    int lrow = lane & 15, quad = lane >> 4;

    const short* Ap = A + ((size_t)((row0 >> 4) + wv) * KI) * 512 + (size_t)lane * 8;
    const short* Wp = W + (size_t)lane * 8;

    short8 areg[KI];
#pragma unroll
    for (int ki = 0; ki < KI; ki++) areg[ki] = *(const short8*)(Ap + (size_t)ki * 512);

    f32x4 acc[CT];
#pragma unroll
    for (int ct = 0; ct < CT; ct++)
#pragma unroll
        for (int i = 0; i < 4; i++) acc[ct][i] = 0.f;

#pragma unroll
    for (int ki = 0; ki < KI; ki++) {
        short8 breg[CT];
#pragma unroll
        for (int ct = 0; ct < CT; ct++)
            breg[ct] = *(const short8*)(Wp + ((size_t)ki * CT + ct) * 512);
#pragma unroll
        for (int ct = 0; ct < CT; ct++)
            acc[ct] = __builtin_amdgcn_mfma_f32_16x16x32_bf16(areg[ki], breg[ct], acc[ct], 0, 0, 0);
    }

    float* Cf = (float*)Cv;
    bf16*  Cb = (bf16*)Cv;
#pragma unroll
    for (int ct = 0; ct < CT; ct++) {
        int gcol = ct * 16 + lrow;
        if (gcol >= M) continue;
        float bv = bias ? bias[gcol] : 0.f;
#pragma unroll
        for (int i = 0; i < 4; i++) {
            int grow = row0 + wv * 16 + quad * 4 + i;
            if (grow >= nrows) continue;
            float v = acc[ct][i] + bv;
            if (ACT == 1) v = fmaxf(v, 0.f);
            if (ACT == 2) v = sigm(v);
            if (ODT == 1) Cb[(size_t)grow * ldc + gcol] = __float2bfloat16(v);
            else          Cf[(size_t)grow * ldc + gcol] = v;
        }
    }

    if (SCORES) {
        float as_c[CT], ad_c[CT];
#pragma unroll
        for (int ct = 0; ct < CT; ct++) {
            int gcol = ct * 16 + lrow;
            as_c[ct] = (gcol < M) ? a_src[gcol] : 0.f;
            ad_c[ct] = (gcol < M) ? a_dst[gcol] : 0.f;
        }
#pragma unroll
        for (int i = 0; i < 4; i++) {
            float ps = 0.f, pd = 0.f;
#pragma unroll
            for (int ct = 0; ct < CT; ct++) {
                ps = fmaf(acc[ct][i], as_c[ct], ps);
                pd = fmaf(acc[ct][i], ad_c[ct], pd);
            }
#pragma unroll
            for (int off = 8; off > 0; off >>= 1) {
                ps += __shfl_down(ps, off);
                pd += __shfl_down(pd, off);
            }
            if (lrow == 0) {
                int grow = row0 + wv * 16 + quad * 4 + i;
                if (grow < nrows) { ssrc[grow] = ps; sdst[grow] = pd; }
            }
        }
    }
}

// ---------------------------------------------------------------------------
// Fused 2-layer MLP branch body: out = relu(W2@sig(W1@a+b1)+b2).
// ADT=0: scalar f32 loads (tiny K). ADT=1: fragment-major bf16 input
// (sequential 1 KB wave-loads). ADT=3: direct vectorized f32x4 fallback.
// W1/W2 fragment-major; output fragment-major.
// ---------------------------------------------------------------------------
template <int ADT, int CT1, int CT2, int KI1>
__device__ __forceinline__ void brmlp_body(
    short* sH,  // [64][CT1*16+8]
    const void* __restrict__ Av, int lda, int aoff,
    const short* __restrict__ W1p, const float* __restrict__ B1,
    const short* __restrict__ W2p, const float* __restrict__ B2,
    short* __restrict__ out, int KIo, int coff, int nrows, int K1)
{
    constexpr int M1 = CT1 * 16;
    constexpr int LDH = M1 + 8;
    constexpr int KI2 = M1 / 32;

    int tid = threadIdx.x;
    int row0 = blockIdx.x * 64;
    int wv = tid >> 6, lane = tid & 63;
    int lrow = lane & 15, quad = lane >> 4;

    // ---- phase 1 ----
    {
        short8 areg[KI1];
        if (ADT == 1) {
            const short* As = (const short*)Av +
                              ((size_t)((row0 >> 4) + wv) * KI1) * 512 + (size_t)lane * 8;
#pragma unroll
            for (int ki = 0; ki < KI1; ki++)
                areg[ki] = *(const short8*)(As + (size_t)ki * 512);
        } else if (ADT == 3) {
            const float* Af = (const float*)Av;
            int arow = row0 + wv * 16 + lrow;
            bool rok = arow < nrows;
            const float* rp = Af + (size_t)arow * lda + aoff;
#pragma unroll
            for (int ki = 0; ki < KI1; ki++) {
                int kb = ki * 32 + quad * 8;
                if (rok && kb + 8 <= K1) {
                    f32x4 a = *(const f32x4*)(rp + kb);
                    f32x4 b = *(const f32x4*)(rp + kb + 4);
#pragma unroll
                    for (int j = 0; j < 4; j++) areg[ki][j] = f2b(a[j]);
#pragma unroll
                    for (int j = 0; j < 4; j++) areg[ki][4 + j] = f2b(b[j]);
                } else if (rok && kb < K1) {
#pragma unroll
                    for (int j = 0; j < 8; j++)
                        areg[ki][j] = (kb + j < K1) ? f2b(rp[kb + j]) : (short)0;
                } else {
#pragma unroll
                    for (int j = 0; j < 8; j++) areg[ki][j] = 0;
                }
            }
        } else {
            const float* Af = (const float*)Av;
            int arow = row0 + wv * 16 + lrow;
            bool rok = arow < nrows;
#pragma unroll
            for (int ki = 0; ki < KI1; ki++)
#pragma unroll
                for (int j = 0; j < 8; j++) {
                    int k = ki * 32 + quad * 8 + j;
                    areg[ki][j] = (rok && k < K1)
                                      ? f2b(Af[(size_t)arow * lda + aoff + k])
                                      : (short)0;
                }
        }

        f32x4 acc[CT1];
#pragma unroll
        for (int ct = 0; ct < CT1; ct++)
#pragma unroll
            for (int i = 0; i < 4; i++) acc[ct][i] = 0.f;

#pragma unroll
        for (int ki = 0; ki < KI1; ki++) {
            short8 breg[CT1];
#pragma unroll
            for (int ct = 0; ct < CT1; ct++)
                breg[ct] = *(const short8*)(W1p + ((size_t)ki * CT1 + ct) * 512 +
                                            (size_t)lane * 8);
#pragma unroll
            for (int ct = 0; ct < CT1; ct++)
                acc[ct] = __builtin_amdgcn_mfma_f32_16x16x32_bf16(areg[ki], breg[ct], acc[ct], 0, 0, 0);
        }
#pragma unroll
        for (int ct = 0; ct < CT1; ct++) {
            int col = ct * 16 + lrow;
            float bv = B1[col];
#pragma unroll
            for (int i = 0; i < 4; i++)
                sH[(wv * 16 + quad * 4 + i) * LDH + col] = f2b(sigm(acc[ct][i] + bv));
        }
    }

    // ---- phase 2 (K2 = M1); per-wave rows, no barrier needed ----
    {
        f32x4 acc[CT2];
#pragma unroll
        for (int ct = 0; ct < CT2; ct++)
#pragma unroll
            for (int i = 0; i < 4; i++) acc[ct][i] = 0.f;

#pragma unroll
        for (int ki = 0; ki < KI2; ki++) {
            short8 a = *(short8*)&sH[(wv * 16 + lrow) * LDH + ki * 32 + quad * 8];
            short8 breg[CT2];
#pragma unroll
            for (int ct = 0; ct < CT2; ct++)
                breg[ct] = *(const short8*)(W2p + ((size_t)ki * CT2 + ct) * 512 +
                                            (size_t)lane * 8);
#pragma unroll
            for (int ct = 0; ct < CT2; ct++)
                acc[ct] = __builtin_amdgcn_mfma_f32_16x16x32_bf16(a, breg[ct], acc[ct], 0, 0, 0);
        }
#pragma unroll
        for (int ct = 0; ct < CT2; ct++) {
            int gcol = ct * 16 + lrow;
            float bv = B2[gcol];
            int c = coff + gcol;
#pragma unroll
            for (int i = 0; i < 4; i++) {
                int grow = row0 + wv * 16 + quad * 4 + i;
                if (grow >= nrows) continue;
                float v = fmaxf(acc[ct][i] + bv, 0.f);
                out[fm_idx(grow, c, KIo)] = f2b(v);
            }
        }
    }
}

template <int ADT, int CT1, int CT2, int KI1>
__global__ __launch_bounds__(256) void brmlp_kernel(
    const void* __restrict__ Av, int lda, int aoff,
    const short* __restrict__ W1p, const float* __restrict__ B1,
    const short* __restrict__ W2p, const float* __restrict__ B2,
    short* __restrict__ out, int KIo, int coff, int nrows, int K1)
{
    __shared__ short sH[64 * (CT1 * 16 + 8)];
    brmlp_body<ADT, CT1, CT2, KI1>(sH, Av, lda, aoff, W1p, B1, W2p, B2,
                                   out, KIo, coff, nrows, K1);
}

// All four MLP branches in one launch (blockIdx.y selects the branch).
__global__ __launch_bounds__(256) void brmlp_all_kernel(
    const float* __restrict__ x_all,
    const short* __restrict__ xs3, const short* __restrict__ xs4,
    const short* __restrict__ s1p, const float* __restrict__ s1b,
    const short* __restrict__ s5p, const float* __restrict__ s5b,
    const short* __restrict__ s2p, const float* __restrict__ s2b,
    const short* __restrict__ s6p, const float* __restrict__ s6b,
    const short* __restrict__ s3p, const float* __restrict__ s3b,
    const short* __restrict__ s7p, const float* __restrict__ s7b,
    const short* __restrict__ s4p, const float* __restrict__ s4b,
    const short* __restrict__ s8p, const float* __restrict__ s8b,
    short* __restrict__ out, int nrows)
{
    __shared__ short sH[64 * 136];
    switch (blockIdx.y) {
    case 0:
        brmlp_body<0, 4, 4, 1>(sH, x_all, 441, 1, s1p, s1b, s5p, s5b,
                               out, 12, 0, nrows, 2);
        break;
    case 1:
        brmlp_body<0, 4, 4, 1>(sH, x_all, 441, 3, s2p, s2b, s6p, s6b,
                               out, 12, 64, nrows, 13);
        break;
    case 2:
        brmlp_body<1, 8, 8, 2>(sH, xs3, 64, 0, s3p, s3b, s7p, s7b,
                               out, 12, 128, nrows, 64);
        break;
    default:
        brmlp_body<1, 8, 8, 12>(sH, xs4, 384, 0, s4p, s4b, s8p, s8b,
                                out, 12, 256, nrows, 384);
        break;
    }
}

// ---------------------------------------------------------------------------
// Fused head: concat(gat3_out, lstm_h) -> lin1(relu) -> lin2(relu) -> lin3.
// ---------------------------------------------------------------------------
__global__ __launch_bounds__(256) void head_kernel(
    const short* __restrict__ xgs, const float* __restrict__ x_all,
    const float* __restrict__ wih, const float* __restrict__ bih,
    const float* __restrict__ bhh,
    const short* __restrict__ w1p, const float* __restrict__ b1,
    const short* __restrict__ w2p, const float* __restrict__ b2,
    const short* __restrict__ w3p, const float* __restrict__ b3,
    float* __restrict__ dout, int n)
{
    __shared__ short sW[20][200];
    __shared__ float sT[64][20];
    __shared__ short sH[64][72];
    __shared__ short sH2[64][72];
    __shared__ short sH3[64][72];

    int tid = threadIdx.x;
    int row0 = blockIdx.x * 64;
    int wv = tid >> 6, lane = tid & 63;
    int lrow = lane & 15, quad = lane >> 4;

    short8 axg[2];
#pragma unroll
    for (int ki = 0; ki < 2; ki++)
        axg[ki] = *(const short8*)(xgs + (((size_t)((row0 >> 4) + wv) * 2 + ki) * 64 +
                                          lane) * 8);

    for (int i = tid; i < 20 * 192; i += 256) {
        int k = i / 192, j = i % 192;
        int gate = j >> 6, jj = j & 63;
        int srow = (gate == 0) ? jj : (gate == 1 ? 128 + jj : 192 + jj);
        sW[k][j] = f2b(wih[srow * 20 + k]);
    }
    for (int i = tid; i < 64 * 20; i += 256) {
        int r = i / 20, k = i % 20;
        int grow = row0 + r;
        sT[r][k] = (grow < n) ? x_all[(size_t)grow * 441 + 421 + k] : 0.f;
    }
    __syncthreads();

    for (int p = 0; p < 16; p++) {
        int idx = p * 256 + tid;
        int r = idx >> 6, j = idx & 63;
        float gi = 0.f, gg = 0.f, go = 0.f;
#pragma unroll
        for (int k = 0; k < 20; k++) {
            float t = sT[r][k];
            gi = fmaf(t, b2f_s((unsigned short)sW[k][j]), gi);
            gg = fmaf(t, b2f_s((unsigned short)sW[k][64 + j]), gg);
            go = fmaf(t, b2f_s((unsigned short)sW[k][128 + j]), go);
        }
        gi += bih[j] + bhh[j];
        gg += bih[128 + j] + bhh[128 + j];
        go += bih[192 + j] + bhh[192 + j];
        float c = sigm(gi) * tanhf(gg);
        float h = sigm(go) * tanhf(c);
        sH[r][j] = f2b(h);
    }
    __syncthreads();

    f32x4 acc[4];
#pragma unroll
    for (int ct = 0; ct < 4; ct++)
#pragma unroll
        for (int i = 0; i < 4; i++) acc[ct][i] = 0.f;
#pragma unroll
    for (int ki = 0; ki < 4; ki++) {
        short8 a = (ki < 2) ? axg[ki]
                            : *(short8*)&sH[wv * 16 + lrow][(ki - 2) * 32 + quad * 8];
        short8 breg[4];
#pragma unroll
        for (int ct = 0; ct < 4; ct++)
            breg[ct] = *(const short8*)(w1p + ((size_t)ki * 4 + ct) * 512 +
                                        (size_t)lane * 8);
#pragma unroll
        for (int ct = 0; ct < 4; ct++)
            acc[ct] = __builtin_amdgcn_mfma_f32_16x16x32_bf16(a, breg[ct], acc[ct], 0, 0, 0);
    }
#pragma unroll
    for (int ct = 0; ct < 4; ct++) {
        int col = ct * 16 + lrow;
        float bv = b1[col];
#pragma unroll
        for (int i = 0; i < 4; i++)
            sH2[wv * 16 + quad * 4 + i][col] = f2b(fmaxf(acc[ct][i] + bv, 0.f));
    }

#pragma unroll
    for (int ct = 0; ct < 4; ct++)
#pragma unroll
        for (int i = 0; i < 4; i++) acc[ct][i] = 0.f;
#pragma unroll
    for (int ki = 0; ki < 2; ki++) {
        short8 a = *(short8*)&sH2[wv * 16 + lrow][ki * 32 + quad * 8];
        short8 breg[4];
#pragma unroll
        for (int ct = 0; ct < 4; ct++)
            breg[ct] = *(const short8*)(w2p + ((size_t)ki * 4 + ct) * 512 +
                                        (size_t)lane * 8);
#pragma unroll
        for (int ct = 0; ct < 4; ct++)
            acc[ct] = __builtin_amdgcn_mfma_f32_16x16x32_bf16(a, breg[ct], acc[ct], 0, 0, 0);
    }
#pragma unroll
    for (int ct = 0; ct < 4; ct++) {
        int col = ct * 16 + lrow;
        float bv = b2[col];
#pragma unroll
        for (int i = 0; i < 4; i++)
            sH3[wv * 16 + quad * 4 + i][col] = f2b(fmaxf(acc[ct][i] + bv, 0.f));
    }

#pragma unroll
    for (int ct = 0; ct < 4; ct++)
#pragma unroll
        for (int i = 0; i < 4; i++) acc[ct][i] = 0.f;
#pragma unroll
    for (int ki = 0; ki < 2; ki++) {
        short8 a = *(short8*)&sH3[wv * 16 + lrow][ki * 32 + quad * 8];
        short8 breg[4];
#pragma unroll
        for (int ct = 0; ct < 4; ct++)
            breg[ct] = *(const short8*)(w3p + ((size_t)ki * 4 + ct) * 512 +
                                        (size_t)lane * 8);
#pragma unroll
        for (int ct = 0; ct < 4; ct++)
            acc[ct] = __builtin_amdgcn_mfma_f32_16x16x32_bf16(a, breg[ct], acc[ct], 0, 0, 0);
    }
#pragma unroll
    for (int ct = 0; ct < 4; ct++) {
        int gcol = ct * 16 + lrow;
        if (gcol >= 56) continue;
        float bv = b3[gcol];
#pragma unroll
        for (int i = 0; i < 4; i++) {
            int grow = row0 + wv * 16 + quad * 4 + i;
            if (grow >= n) continue;
            dout[(size_t)grow * 56 + gcol] = acc[ct][i] + bv;
        }
    }
}

// ---------------------------------------------------------------------------
// Fused GAT aggregation, 8-deep gather unroll. Output fragment-major.
// ---------------------------------------------------------------------------
template <int FPL, int KIo>
__global__ __launch_bounds__(256) void gat_fused_kernel(
    const bf16* __restrict__ hw, const int* __restrict__ rowptr,
    const int* __restrict__ colidx, const float* __restrict__ ss,
    const float* __restrict__ sd, const float* __restrict__ bias,
    short* __restrict__ out, int n, int F)
{
    int wv = threadIdx.x >> 6, lane = threadIdx.x & 63;
    int node = blockIdx.x * 4 + wv;
    if (node >= n) return;
    const unsigned short* hwu = (const unsigned short*)hw;
    float sdn = sd[node];
    float wself = expf(lrelu(ss[node] + sdn));
    float a0, a1 = 0.f;
    if (FPL == 2) {
        unsigned u = *(const unsigned*)(hwu + (size_t)node * F + 2 * lane);
        a0 = wself * lo_bf(u);
        a1 = wself * hi_bf(u);
    } else {
        a0 = wself * b2f_s(hwu[(size_t)node * F + lane]);
    }
    int e0 = rowptr[node];
    int deg = rowptr[node + 1] - e0;
    float den_l = 0.f;
    for (int c0 = 0; c0 < deg; c0 += 64) {
        int mye = c0 + lane;
        int s = 0;
        float w = 0.f;
        if (mye < deg) {
            s = colidx[e0 + mye];
            w = expf(lrelu(ss[s] + sdn));
        }
        den_l += w;
        int cnt = min(64, deg - c0);
        int j = 0;
        for (; j + 7 < cnt; j += 8) {
            int sx[8];
            float wx[8];
#pragma unroll
            for (int q = 0; q < 8; q++) {
                sx[q] = __shfl(s, j + q);
                wx[q] = __shfl(w, j + q);
            }
            if (FPL == 2) {
                unsigned ux[8];
#pragma unroll
                for (int q = 0; q < 8; q++)
                    ux[q] = *(const unsigned*)(hwu + (size_t)sx[q] * F + 2 * lane);
#pragma unroll
                for (int q = 0; q < 8; q++) {
                    a0 = fmaf(wx[q], lo_bf(ux[q]), a0);
                    a1 = fmaf(wx[q], hi_bf(ux[q]), a1);
                }
            } else {
                float hx[8];
#pragma unroll
                for (int q = 0; q < 8; q++)
                    hx[q] = b2f_s(hwu[(size_t)sx[q] * F + lane]);
#pragma unroll
                for (int q = 0; q < 8; q++) a0 = fmaf(wx[q], hx[q], a0);
            }
        }
        for (; j + 3 < cnt; j += 4) {
            int s0 = __shfl(s, j), s1 = __shfl(s, j + 1);
            int s2 = __shfl(s, j + 2), s3 = __shfl(s, j + 3);
            float w0 = __shfl(w, j), w1v = __shfl(w, j + 1);
            float w2v = __shfl(w, j + 2), w3v = __shfl(w, j + 3);
            if (FPL == 2) {
                unsigned u0 = *(const unsigned*)(hwu + (size_t)s0 * F + 2 * lane);
                unsigned u1 = *(const unsigned*)(hwu + (size_t)s1 * F + 2 * lane);
                unsigned u2 = *(const unsigned*)(hwu + (size_t)s2 * F + 2 * lane);
                unsigned u3 = *(const unsigned*)(hwu + (size_t)s3 * F + 2 * lane);
                a0 = fmaf(w0, lo_bf(u0), a0);  a1 = fmaf(w0, hi_bf(u0), a1);
                a0 = fmaf(w1v, lo_bf(u1), a0); a1 = fmaf(w1v, hi_bf(u1), a1);
                a0 = fmaf(w2v, lo_bf(u2), a0); a1 = fmaf(w2v, hi_bf(u2), a1);
                a0 = fmaf(w3v, lo_bf(u3), a0); a1 = fmaf(w3v, hi_bf(u3), a1);
            } else {
                float h0 = b2f_s(hwu[(size_t)s0 * F + lane]);
                float h1 = b2f_s(hwu[(size_t)s1 * F + lane]);
                float h2 = b2f_s(hwu[(size_t)s2 * F + lane]);
                float h3 = b2f_s(hwu[(size_t)s3 * F + lane]);
                a0 = fmaf(w0, h0, a0);
                a0 = fmaf(w1v, h1, a0);
                a0 = fmaf(w2v, h2, a0);
                a0 = fmaf(w3v, h3, a0);
            }
        }
        for (; j < cnt; j++) {
            int s0 = __shfl(s, j);
            float w0 = __shfl(w, j);
            if (FPL == 2) {
                unsigned u0 = *(const unsigned*)(hwu + (size_t)s0 * F + 2 * lane);
                a0 = fmaf(w0, lo_bf(u0), a0);
                a1 = fmaf(w0, hi_bf(u0), a1);
            } else {
                a0 = fmaf(w0, b2f_s(hwu[(size_t)s0 * F + lane]), a0);
            }
        }
    }
#pragma unroll
    for (int off = 32; off > 0; off >>= 1) den_l += __shfl_xor(den_l, off);
    float inv = 1.f / (den_l + wself);
    int rb = node >> 4, nr = node & 15;
    if (FPL == 2) {
        float v0 = fmaxf(a0 * inv + bias[2 * lane], 0.f);
        float v1 = fmaxf(a1 * inv + bias[2 * lane + 1], 0.f);
        size_t uidx = ((size_t)rb * KIo + (lane >> 4)) * 256 +
                      (size_t)((lane >> 2) & 3) * 64 + nr * 4 + (lane & 3);
        ((unsigned*)out)[uidx] = pack_bf(v0, v1);
    } else {
        float v0 = fmaxf(a0 * inv + bias[lane], 0.f);
        size_t sidx = ((size_t)rb * KIo + (lane >> 5)) * 512 +
                      (size_t)((lane >> 3) & 3) * 128 + nr * 8 + (lane & 7);
        out[sidx] = f2b(v0);
    }
}

// ---------------------------------------------------------------------------
// Bucketed CSR build (write-amp-free):
//   bhist -> bscan -> bpart (bucket-partitioned pairs) -> bcsr (one block
//   per bucket: LDS per-node count + scan + scatter within a private window).
// ---------------------------------------------------------------------------
__global__ __launch_bounds__(256) void bhist_kernel(const int* __restrict__ dst,
                                                    int* __restrict__ bcnt, int e)
{
    __shared__ int l[NB];
    for (int i = threadIdx.x; i < NB; i += 256) l[i] = 0;
    __syncthreads();
    for (int i = blockIdx.x * blockDim.x + threadIdx.x; i < e;
         i += gridDim.x * blockDim.x)
        atomicAdd(&l[dst[i] >> 8], 1);
    __syncthreads();
    for (int i = threadIdx.x; i < NB; i += 256)
        if (l[i]) atomicAdd(&bcnt[i], l[i]);
}

__global__ __launch_bounds__(256) void bscan_kernel(
    const int* __restrict__ bcnt, int* __restrict__ boff,
    int* __restrict__ bcur, int* __restrict__ rowptr, int n, int e)
{
    __shared__ int tmp[256];
    int tid = threadIdx.x;
    int v = (tid < NB) ? bcnt[tid] : 0;
    tmp[tid] = v;
    __syncthreads();
    for (int off = 1; off < 256; off <<= 1) {
        int t = (tid >= off) ? tmp[tid - off] : 0;
        __syncthreads();
        tmp[tid] += t;
        __syncthreads();
    }
    int excl = tmp[tid] - v;
    if (tid < NB) { boff[tid] = excl; bcur[tid] = excl; }
    if (tid == 0) { boff[NB] = e; rowptr[n] = e; }
}

__global__ __launch_bounds__(256) void bpart_kernel(
    const int* __restrict__ src, const int* __restrict__ dst,
    int* __restrict__ bcur, int2* __restrict__ pairs, int e)
{
    __shared__ int lcnt[NB];
    __shared__ int lbase[NB];
    const int TILE = 2048;
    for (long long t0 = (long long)blockIdx.x * TILE; t0 < e;
         t0 += (long long)gridDim.x * TILE) {
        for (int i = threadIdx.x; i < NB; i += 256) lcnt[i] = 0;
        __syncthreads();
        int rank[8], bb[8], sv[8], dv[8];
#pragma unroll
        for (int k = 0; k < 8; k++) {
            int i = (int)t0 + k * 256 + threadIdx.x;
            bb[k] = -1;
            if (i < e) {
                int d = dst[i];
                sv[k] = src[i];
                dv[k] = d;
                bb[k] = d >> 8;
                rank[k] = atomicAdd(&lcnt[bb[k]], 1);
            }
        }
        __syncthreads();
        for (int i = threadIdx.x; i < NB; i += 256)
            lbase[i] = lcnt[i] ? atomicAdd(&bcur[i], lcnt[i]) : 0;
        __syncthreads();
#pragma unroll
        for (int k = 0; k < 8; k++)
            if (bb[k] >= 0)
                pairs[(size_t)lbase[bb[k]] + rank[k]] = make_int2(sv[k], dv[k]);
        __syncthreads();
    }
}

__global__ __launch_bounds__(256) void bcsr_kernel(
    const int2* __restrict__ pairs, const int* __restrict__ boff,
    int* __restrict__ rowptr, int* __restrict__ colidx, int n)
{
    __shared__ int ncnt[256];
    __shared__ int tmp[256];
    int tid = threadIdx.x, b = blockIdx.x;
    int base = boff[b], end = boff[b + 1];
    ncnt[tid] = 0;
    __syncthreads();
    for (int i = base + tid; i < end; i += 256)
        atomicAdd(&ncnt[pairs[i].y & 255], 1);
    __syncthreads();
    int v = ncnt[tid];
    tmp[tid] = v;
    __syncthreads();
    for (int off = 1; off < 256; off <<= 1) {
        int t = (tid >= off) ? tmp[tid - off] : 0;
        __syncthreads();
        tmp[tid] += t;
        __syncthreads();
    }
    int excl = base + tmp[tid] - v;
    int node = (b << 8) + tid;
    if (node < n) rowptr[node] = excl;
    __syncthreads();
    ncnt[tid] = excl;
    __syncthreads();
    for (int i = base + tid; i < end; i += 256) {
        int2 p = pairs[i];
        int pos = atomicAdd(&ncnt[p.y & 255], 1);
        colidx[pos] = p.x;
    }
}

// ---------------------------------------------------------------------------
// Legacy CSR build (fallback if workspace too small for the pairs buffer).
// ---------------------------------------------------------------------------
__global__ void count_kernel(const int* __restrict__ dst, int* __restrict__ cnt,
                             int e)
{
    for (int i = blockIdx.x * blockDim.x + threadIdx.x; i < e;
         i += gridDim.x * blockDim.x)
        atomicAdd(cnt + dst[i], 1);
}

#define SCAN_BLOCKS 256

__global__ __launch_bounds__(256) void scan_local_kernel(
    const int* __restrict__ cnt, int* __restrict__ rowptr,
    int* __restrict__ bsum, int n, int chunk)
{
    __shared__ int tmp[256];
    int b = blockIdx.x, tid = threadIdx.x;
    int i = b * chunk + tid;
    int v = (tid < chunk && i < n) ? cnt[i] : 0;
    tmp[tid] = v;
    __syncthreads();
    for (int off = 1; off < 256; off <<= 1) {
        int t = (tid >= off) ? tmp[tid - off] : 0;
        __syncthreads();
        tmp[tid] += t;
        __syncthreads();
    }
    if (tid < chunk && i < n) rowptr[i] = tmp[tid] - v;
    if (tid == 255) bsum[b] = tmp[255];
}

__global__ __launch_bounds__(256) void scan_bsums_kernel(
    int* __restrict__ bsum, int* __restrict__ rowptr, int n)
{
    __shared__ int tmp[256];
    int tid = threadIdx.x;
    int v = bsum[tid];
    tmp[tid] = v;
    __syncthreads();
    for (int off = 1; off < 256; off <<= 1) {
        int t = (tid >= off) ? tmp[tid - off] : 0;
        __syncthreads();
        tmp[tid] += t;
        __syncthreads();
    }
    bsum[tid] = tmp[tid] - v;
    if (tid == 255) rowptr[n] = tmp[255];
}

__global__ __launch_bounds__(256) void scan_add_kernel(
    int* __restrict__ rowptr, int* __restrict__ nextp,
    const int* __restrict__ bsum, int n, int chunk)
{
    int b = blockIdx.x, tid = threadIdx.x;
    int i = b * chunk + tid;
    if (tid < chunk && i < n) {
        int v = rowptr[i] + bsum[b];
        rowptr[i] = v;
        nextp[i] = v;
    }
}

__global__ void fill_kernel(const int* __restrict__ src,
                            const int* __restrict__ dst,
                            int* __restrict__ nextp, int* __restrict__ colidx,
                            int e)
{
    for (int i = blockIdx.x * blockDim.x + threadIdx.x; i < e;
         i += gridDim.x * blockDim.x) {
        int pos = atomicAdd(nextp + dst[i], 1);
        colidx[pos] = src[i];
    }
}

// ---------------------------------------------------------------------------
extern "C" void kernel_launch(void* const* d_in, const int* in_sizes, int n_in,
                              void* d_out, int out_size, void* d_ws,
                              size_t ws_size, hipStream_t stream)
{
    const int N = N_NODES;
    const int E = N_EDGES;

    const float* x_all = (const float*)d_in[0];
    const int* edges = (const int*)d_in[1];
    const int* e_src = edges;
    const int* e_dst = edges + E;

    const float* sep1_w = (const float*)d_in[2];  const float* sep1_b = (const float*)d_in[3];
    const float* sep2_w = (const float*)d_in[4];  const float* sep2_b = (const float*)d_in[5];
    const float* sep3_w = (const float*)d_in[6];  const float* sep3_b = (const float*)d_in[7];
    const float* sep4_w = (const float*)d_in[8];  const float* sep4_b = (const float*)d_in[9];
    const float* sep5_w = (const float*)d_in[10]; const float* sep5_b = (const float*)d_in[11];
    const float* sep6_w = (const float*)d_in[12]; const float* sep6_b = (const float*)d_in[13];
    const float* sep7_w = (const float*)d_in[14]; const float* sep7_b = (const float*)d_in[15];
    const float* sep8_w = (const float*)d_in[16]; const float* sep8_b = (const float*)d_in[17];
    const float* conv1_w = (const float*)d_in[18];
    const float* conv1_as = (const float*)d_in[19];
    const float* conv1_ad = (const float*)d_in[20];
    const float* conv1_b = (const float*)d_in[21];
    const float* conv2_w = (const float*)d_in[22];
    const float* conv2_as = (const float*)d_in[23];
    const float* conv2_ad = (const float*)d_in[24];
    const float* conv2_b = (const float*)d_in[25];
    const float* conv3_w = (const float*)d_in[26];
    const float* conv3_as = (const float*)d_in[27];
    const float* conv3_ad = (const float*)d_in[28];
    const float* conv3_b = (const float*)d_in[29];
    const float* lstm_wih = (const float*)d_in[30];
    const float* lstm_bih = (const float*)d_in[32];
    const float* lstm_bhh = (const float*)d_in[33];
    const float* lin1_w = (const float*)d_in[34]; const float* lin1_b = (const float*)d_in[35];
    const float* lin2_w = (const float*)d_in[36]; const float* lin2_b = (const float*)d_in[37];
    const float* lin3_w = (const float*)d_in[38]; const float* lin3_b = (const float*)d_in[39];

    char* ws = (char*)d_ws;
    size_t off = 0;
    auto alloc = [&](size_t bytes) {
        void* p = ws + off;
        off += (bytes + 255) & ~(size_t)255;
        return p;
    };
    short* x0 = (short*)alloc((size_t)NP * 384 * 2);  // FM concat / C ping / xg
    short* Bb = (short*)alloc((size_t)NP * 128 * 2);  // hw buffer (row-major)
    float* ssrc = (float*)alloc((size_t)N * 4);
    float* sdst = (float*)alloc((size_t)N * 4);
    int* rowptr = (int*)alloc((size_t)(N + 1) * 4);
    int* nextp  = (int*)alloc((size_t)N * 4);
    int* cnt    = (int*)alloc((size_t)N * 4);
    int* bsum   = (int*)alloc((size_t)SCAN_BLOCKS * 4);
    int* colidx = (int*)alloc((size_t)E * 4);
    int* bcnt   = (int*)alloc((size_t)NB * 4);
    int* boff   = (int*)alloc((size_t)(NB + 1) * 4);
    int* bcur   = (int*)alloc((size_t)NB * 4);

    short* conv1p = (short*)alloc((size_t)128 * 384 * 2);
    short* conv2p = (short*)alloc((size_t)128 * 128 * 2);
    short* conv3p = (short*)alloc((size_t)64 * 128 * 2);
    short* sep1p  = (short*)alloc((size_t)64 * 32 * 2);
    short* sep2p  = (short*)alloc((size_t)64 * 32 * 2);
    short* sep3p  = (short*)alloc((size_t)128 * 64 * 2);
    short* sep4p  = (short*)alloc((size_t)128 * 384 * 2);
    short* sep5p  = (short*)alloc((size_t)64 * 64 * 2);
    short* sep6p  = (short*)alloc((size_t)64 * 64 * 2);
    short* sep7p  = (short*)alloc((size_t)128 * 128 * 2);
    short* sep8p  = (short*)alloc((size_t)128 * 128 * 2);
    short* lin1p  = (short*)alloc((size_t)64 * 128 * 2);
    short* lin2p  = (short*)alloc((size_t)64 * 64 * 2);
    short* lin3p  = (short*)alloc((size_t)64 * 64 * 2);

    size_t need_pairs = off + (size_t)E * 8 + 1024;
    bool binfill = ws_size >= need_pairs;
    int2* pairs = binfill ? (int2*)alloc((size_t)E * 8) : nullptr;

    size_t need_xs = off + (size_t)NP * 64 * 2 + (size_t)NP * 384 * 2 + 1024;
    bool packx = ws_size >= need_xs;
    short* xs3 = packx ? (short*)alloc((size_t)NP * 64 * 2) : nullptr;
    short* xs4 = packx ? (short*)alloc((size_t)NP * 384 * 2) : nullptr;

    short* C  = x0;   // GAT ping buffer (N,128) FM KIo=4
    short* xg = x0;   // GAT3 out (N,64) FM KIo=2

    dim3 blk(256);
    int gx = NP / 64;  // 782
    int nb4 = (N + 3) / 4;

    // --- CSR build ---
    if (binfill) {
        hipMemsetAsync(bcnt, 0, (size_t)NB * 4, stream);
        bhist_kernel<<<1024, 256, 0, stream>>>(e_dst, bcnt, E);
        bscan_kernel<<<1, 256, 0, stream>>>(bcnt, boff, bcur, rowptr, N, E);
        bpart_kernel<<<(E + 2047) / 2048, 256, 0, stream>>>(e_src, e_dst, bcur,
                                                            pairs, E);
        bcsr_kernel<<<NB, 256, 0, stream>>>(pairs, boff, rowptr, colidx, N);
    } else {
        int chunk = (N + SCAN_BLOCKS - 1) / SCAN_BLOCKS;
        hipMemsetAsync(cnt, 0, (size_t)N * 4, stream);
        count_kernel<<<1024, 256, 0, stream>>>(e_dst, cnt, E);
        scan_local_kernel<<<SCAN_BLOCKS, 256, 0, stream>>>(cnt, rowptr, bsum, N, chunk);
        scan_bsums_kernel<<<1, 256, 0, stream>>>(bsum, rowptr, N);
        scan_add_kernel<<<SCAN_BLOCKS, 256, 0, stream>>>(rowptr, nextp, bsum, N, chunk);
        fill_kernel<<<1024, 256, 0, stream>>>(e_src, e_dst, nextp, colidx, E);
    }

    // --- weight pack args (shared by both paths) ---
    PackArgs pa{};
    unsigned long long total = 0;
    {
        int np = 0;
        auto addp = [&](const float* src, short* dst, int lda, int M, int K,
                        int CT, int KI) {
            pa.d[np].src = src; pa.d[np].dst = dst; pa.d[np].lda = lda;
            pa.d[np].M = M; pa.d[np].K = K; pa.d[np].CT = CT; pa.d[np].KI = KI;
            pa.sz[np] = (unsigned long long)CT * KI * 512;
            total += pa.sz[np];
            np++;
        };
        addp(conv1_w, conv1p, 384, 128, 384, 8, 12);
        addp(sep4_w, sep4p, 365, 128, 365, 8, 12);
        addp(conv2_w, conv2p, 128, 128, 128, 8, 4);
        addp(sep7_w, sep7p, 128, 128, 128, 8, 4);
        addp(sep8_w, sep8p, 128, 128, 128, 8, 4);
        addp(conv3_w, conv3p, 128, 64, 128, 4, 4);
        addp(lin1_w, lin1p, 128, 64, 128, 4, 4);
        addp(sep3_w, sep3p, 40, 128, 40, 8, 2);
        addp(sep5_w, sep5p, 64, 64, 64, 4, 2);
        addp(sep6_w, sep6p, 64, 64, 64, 4, 2);
        addp(lin2_w, lin2p, 64, 64, 64, 4, 2);
        addp(lin3_w, lin3p, 64, 56, 64, 4, 2);
        addp(sep1_w, sep1p, 2, 64, 2, 4, 1);
        addp(sep2_w, sep2p, 13, 64, 13, 4, 1);
        pa.n = np;
    }

    if (packx) {
        // --- fused packer: x-transpose tiles + weight tensors, one launch ---
        pack_misc_kernel<<<RB16 + 256, blk, 0, stream>>>(
            x_all, xs4, xs3, N, pa, total, RB16);
        // --- all four MLP branches in one launch ---
        brmlp_all_kernel<<<dim3(gx, 4), blk, 0, stream>>>(
            x_all, xs3, xs4,
            sep1p, sep1_b, sep5p, sep5_b,
            sep2p, sep2_b, sep6p, sep6_b,
            sep3p, sep3_b, sep7p, sep7_b,
            sep4p, sep4_b, sep8p, sep8_b,
            x0, N);
    } else {
        pack_all_kernel<<<512, 256, 0, stream>>>(pa, total);
        brmlp_kernel<0, 4, 4, 1><<<gx, blk, 0, stream>>>(
            x_all, 441, 1, sep1p, sep1_b, sep5p, sep5_b, x0, 12, 0, N, 2);
        brmlp_kernel<0, 4, 4, 1><<<gx, blk, 0, stream>>>(
            x_all, 441, 3, sep2p, sep2_b, sep6p, sep6_b, x0, 12, 64, N, 13);
        brmlp_kernel<3, 8, 8, 2><<<gx, blk, 0, stream>>>(
            x_all, 441, 16, sep3p, sep3_b, sep7p, sep7_b, x0, 12, 128, N, 40);
        brmlp_kernel<3, 8, 8, 12><<<gx, blk, 0, stream>>>(
            x_all, 441, 56, sep4p, sep4_b, sep8p, sep8_b, x0, 12, 256, N, 365);
    }

    // --- GAT layers (scores fused into GEMM epilogue; FM operand loads) ---
    dgemm_kernel<0, 1, 8, 12, 1><<<gx, blk, 0, stream>>>(
        x0, conv1p, nullptr, Bb, 128, N, 128,
        conv1_as, conv1_ad, ssrc, sdst);
    gat_fused_kernel<2, 4><<<nb4, 256, 0, stream>>>(
        (const bf16*)Bb, rowptr, colidx, ssrc, sdst, conv1_b, C, N, 128);

    dgemm_kernel<0, 1, 8, 4, 1><<<gx, blk, 0, stream>>>(
        C, conv2p, nullptr, Bb, 128, N, 128,
        conv2_as, conv2_ad, ssrc, sdst);
    gat_fused_kernel<2, 4><<<nb4, 256, 0, stream>>>(
        (const bf16*)Bb, rowptr, colidx, ssrc, sdst, conv2_b, C, N, 128);

    dgemm_kernel<0, 1, 4, 4, 1><<<gx, blk, 0, stream>>>(
        C, conv3p, nullptr, Bb, 64, N, 64,
        conv3_as, conv3_ad, ssrc, sdst);
    gat_fused_kernel<1, 2><<<nb4, 256, 0, stream>>>(
        (const bf16*)Bb, rowptr, colidx, ssrc, sdst, conv3_b, xg, N, 64);

    // --- fused head: lstm + lin1 + lin2 + lin3 ---
    head_kernel<<<gx, blk, 0, stream>>>(
        xg, x_all, lstm_wih, lstm_bih, lstm_bhh,
        lin1p, lin1_b, lin2p, lin2_b, lin3p, lin3_b,
        (float*)d_out, N);
}